// Round 4
// baseline (23029.988 us; speedup 1.0000x reference)
//
#include <hip/hip_runtime.h>
#include <math.h>

#define TQ 256
#define DQ 512
#define GQ 2048
#define NWG 32

typedef __attribute__((ext_vector_type(8))) short bf16x8;
typedef __attribute__((ext_vector_type(4))) float f32x4;

__device__ __forceinline__ unsigned f2bf(float x) {
    unsigned u = __builtin_bit_cast(unsigned, x);
    return (u + 0x7fffu + ((u >> 16) & 1u)) >> 16;
}
__device__ __forceinline__ float bf2f(unsigned s) {
    return __builtin_bit_cast(float, s << 16);
}
__device__ __forceinline__ float sigf(float x) { return 1.f / (1.f + __expf(-x)); }
__device__ __forceinline__ float tanhfast(float x) { return 1.f - 2.f / (__expf(2.f * x) + 1.f); }

__device__ __forceinline__ void store_short_coh(unsigned short* p, unsigned v) {
    asm volatile("global_store_short %0, %1, off sc0 sc1" :: "v"(p), "v"(v) : "memory");
}

__device__ __forceinline__ bf16x8 load_afrag(const unsigned* pw) {
    union { unsigned w[4]; bf16x8 s; } cv;
#pragma unroll
    for (int i = 0; i < 4; ++i)
        cv.w[i] = __hip_atomic_load(pw + i, __ATOMIC_RELAXED, __HIP_MEMORY_SCOPE_AGENT);
    return cv.s;
}

// ---------------- embedding + predicate concat -> xT[t][d][b] ----------------
__global__ __launch_bounds__(256) void k_embed(const int* __restrict__ wid,
                                               const int* __restrict__ pid,
                                               const float* __restrict__ emb,
                                               float* __restrict__ xT) {
    __shared__ float Ls[64][65];
    int t = blockIdx.x;
    int d0 = blockIdx.y * 64;
    int tid = threadIdx.x;
    int l = tid & 63;
    int grp = tid >> 6;
#pragma unroll 4
    for (int bb = 0; bb < 16; ++bb) {
        int b = grp * 16 + bb;
        int d = d0 + l;
        float v;
        if (d < 511) v = emb[(size_t)wid[b * TQ + t] * 511 + d];
        else         v = (float)pid[b * TQ + t];
        Ls[l][b] = v;
    }
    __syncthreads();
#pragma unroll 4
    for (int dd = 0; dd < 16; ++dd) {
        int dl = grp * 16 + dd;
        xT[((size_t)t * DQ + d0 + dl) * 64 + l] = Ls[dl][l];
    }
}

// ---------------- U -> fragment-linear bf16 hi/lo (once, all layers) --------
__global__ __launch_bounds__(256) void k_convU(const float* __restrict__ Us,
                                               unsigned short* __restrict__ Ufh,
                                               unsigned short* __restrict__ Ufl) {
    int t = blockIdx.x * 256 + threadIdx.x;   // lay*2^20 + k*2048 + col
    int col = t & 2047;
    int k = (t >> 11) & 511;
    int lay = t >> 20;
    float v = Us[t];
    unsigned hi = f2bf(v);
    unsigned lo = f2bf(v - bf2f(hi));
    int g = col >> 9;
    int wgc = (col >> 4) & 31;
    int u = col & 15;
    int kt = k >> 5;
    int lane = ((k >> 3) & 3) * 16 + u;
    int jj = k & 7;
    size_t idx = (((((size_t)lay * NWG + wgc) * 4 + g) * 16 + kt) * 64 + lane) * 8 + jj;
    Ufh[idx] = (unsigned short)hi;
    Ufl[idx] = (unsigned short)lo;
}

// ---------------- preF[sl][wg][g][b][u] = xT(t_in) @ W + bias ----------------
__global__ __launch_bounds__(256) void k_pre(const float* __restrict__ xT,
                                             const float* __restrict__ W,
                                             const float* __restrict__ bias,
                                             float* __restrict__ preF,
                                             int s0, int flip) {
    __shared__ float As[16][68];   // [k][b]
    __shared__ float Bs[16][68];   // [k][n]
    int sl = blockIdx.x;
    int nt = blockIdx.y;
    int s = s0 + sl;
    int t_in = flip ? (TQ - 1 - s) : s;
    int tid = threadIdx.x;
    int tr = tid >> 4;              // 0..15 -> b quad
    int tc = tid & 15;              // 0..15 -> n quad
    int lk = tid >> 4;
    int lb4 = (tid & 15) * 4;

    float acc[4][4];
#pragma unroll
    for (int i = 0; i < 4; ++i)
#pragma unroll
        for (int jc = 0; jc < 4; ++jc) acc[i][jc] = 0.f;

    const float* xTt = xT + (size_t)t_in * DQ * 64;

    for (int kt = 0; kt < DQ; kt += 16) {
        *(float4*)&As[lk][lb4] = *(const float4*)&xTt[(size_t)(kt + lk) * 64 + lb4];
        *(float4*)&Bs[lk][lb4] = *(const float4*)&W[(size_t)(kt + lk) * GQ + nt * 64 + lb4];
        __syncthreads();
#pragma unroll
        for (int k = 0; k < 16; ++k) {
            float4 av = *(const float4*)&As[k][tr * 4];
            float4 bv = *(const float4*)&Bs[k][tc * 4];
            float a[4] = {av.x, av.y, av.z, av.w};
            float bb[4] = {bv.x, bv.y, bv.z, bv.w};
#pragma unroll
            for (int i = 0; i < 4; ++i)
#pragma unroll
                for (int jc = 0; jc < 4; ++jc) acc[i][jc] += a[i] * bb[jc];
        }
        __syncthreads();
    }
#pragma unroll
    for (int jc = 0; jc < 4; ++jc) {
        int col = nt * 64 + tc * 4 + jc;
        float bv = bias[col];
        int g = col >> 9;
        int wgc = (col >> 4) & 31;
        int uu = col & 15;
        size_t base = (((size_t)sl * NWG + wgc) * 4 + g) * 64;
#pragma unroll
        for (int i = 0; i < 4; ++i)
            preF[(base + tr * 4 + i) * 16 + uu] = acc[i][jc] + bv;
    }
}

// ---------------- persistent LSTM layer: split-bf16 MFMA recurrence ----------
// 32 WGs x 256 thr (4 waves). WG owns 16 hidden units (64 gate cols).
// wave w: kh = w>>1 (k-half of 512), mh = w&1 (batch half of 64).
// h crosses steps as bf16 hi/lo fragments (ping-pong); c, carried-h in regs.
__global__ __launch_bounds__(256, 1) void k_layer(
    const unsigned short* __restrict__ Ufh,
    const unsigned short* __restrict__ Ufl,
    const float* __restrict__ preF,
    const int* __restrict__ mask,
    unsigned short* __restrict__ hf,    // [parity][hi/lo][32768]
    float* __restrict__ hT,             // [j][b] carried h (chunk boundary)
    float* __restrict__ cT,             // [j][b]
    float* __restrict__ xoutT,          // [s][j][b]
    unsigned* __restrict__ bar,
    int s0, int nsteps, int flip)
{
    __shared__ float part[4096];        // 16 KB [mt][g][r][lane]
    int wg = blockIdx.x;
    int tid = threadIdx.x;
    int w = tid >> 6, l = tid & 63;
    int kh = w >> 1, mh = w & 1;
    int u = l & 15, lh = l >> 4;
    int j = wg * 16 + u;
    int ktW = wg >> 1;
    int laneW_hi = ((wg * 2 + (u >> 3)) & 3) * 16;

    float creg[8], hprev[8];
    if (kh == 0) {
#pragma unroll
        for (int mt2 = 0; mt2 < 2; ++mt2)
#pragma unroll
            for (int r = 0; r < 4; ++r) {
                int b = mh * 32 + mt2 * 16 + lh * 4 + r;
                creg[mt2 * 4 + r] = cT[j * 64 + b];
                hprev[mt2 * 4 + r] = hT[j * 64 + b];
            }
    }

    for (int sl = 0; sl < nsteps; ++sl) {
        int s = s0 + sl;
        int p = s & 1;
        const unsigned* hrH = (const unsigned*)(hf + ((size_t)p * 2 + 0) * 32768);
        const unsigned* hrL = (const unsigned*)(hf + ((size_t)p * 2 + 1) * 32768);
        unsigned short* hwH = hf + ((size_t)(p ^ 1) * 2 + 0) * 32768;
        unsigned short* hwL = hf + ((size_t)(p ^ 1) * 2 + 1) * 32768;

        // prefetch finish operands (HBM pre + mask) early
        float pz[2][4][4];
        int mv[8];
        if (kh == 0) {
            int t_in = flip ? (TQ - 1 - s) : s;
#pragma unroll
            for (int mt2 = 0; mt2 < 2; ++mt2)
#pragma unroll
                for (int r = 0; r < 4; ++r) {
                    int b = mh * 32 + mt2 * 16 + lh * 4 + r;
                    mv[mt2 * 4 + r] = mask[b * TQ + t_in];
#pragma unroll
                    for (int g = 0; g < 4; ++g)
                        pz[mt2][g][r] =
                            preF[((((size_t)sl * NWG + wg) * 4 + g) * 64 + b) * 16 + u];
                }
        }

        // load all A (h) fragments for this wave's (m-half, k-half)
        bf16x8 AH[2][8], AL[2][8];
#pragma unroll
        for (int kk = 0; kk < 8; ++kk) {
            int kt = kh * 8 + kk;
#pragma unroll
            for (int mt2 = 0; mt2 < 2; ++mt2) {
                int mt = mh * 2 + mt2;
                AH[mt2][kk] = load_afrag(hrH + ((size_t)(mt * 16 + kt) * 64 + l) * 4);
                AL[mt2][kk] = load_afrag(hrL + ((size_t)(mt * 16 + kt) * 64 + l) * 4);
            }
        }

        f32x4 acc[2][4];
        f32x4 zv = {0.f, 0.f, 0.f, 0.f};
#pragma unroll
        for (int mt2 = 0; mt2 < 2; ++mt2)
#pragma unroll
            for (int g = 0; g < 4; ++g) acc[mt2][g] = zv;

#pragma unroll 2
        for (int kk = 0; kk < 8; ++kk) {
            int kt = kh * 8 + kk;
#pragma unroll
            for (int g = 0; g < 4; ++g) {
                bf16x8 bH = *(const bf16x8*)(Ufh + ((((size_t)wg * 4 + g) * 16 + kt) * 64 + l) * 8);
                bf16x8 bL = *(const bf16x8*)(Ufl + ((((size_t)wg * 4 + g) * 16 + kt) * 64 + l) * 8);
#pragma unroll
                for (int mt2 = 0; mt2 < 2; ++mt2) {
                    acc[mt2][g] = __builtin_amdgcn_mfma_f32_16x16x32_bf16(AH[mt2][kk], bH, acc[mt2][g], 0, 0, 0);
                    acc[mt2][g] = __builtin_amdgcn_mfma_f32_16x16x32_bf16(AL[mt2][kk], bH, acc[mt2][g], 0, 0, 0);
                    acc[mt2][g] = __builtin_amdgcn_mfma_f32_16x16x32_bf16(AH[mt2][kk], bL, acc[mt2][g], 0, 0, 0);
                }
            }
        }

        // cross-k-half reduction: kh=1 waves dump partials
        if (kh == 1) {
#pragma unroll
            for (int mt2 = 0; mt2 < 2; ++mt2)
#pragma unroll
                for (int g = 0; g < 4; ++g)
#pragma unroll
                    for (int r = 0; r < 4; ++r)
                        part[(((mh * 2 + mt2) * 4 + g) * 4 + r) * 64 + l] = acc[mt2][g][r];
        }
        __syncthreads();

        if (kh == 0) {
#pragma unroll
            for (int mt2 = 0; mt2 < 2; ++mt2) {
#pragma unroll
                for (int r = 0; r < 4; ++r) {
                    int q = mt2 * 4 + r;
                    int b = mh * 32 + mt2 * 16 + lh * 4 + r;
                    int pb = ((mh * 2 + mt2) * 4) * 4 + r;
                    float z0 = pz[mt2][0][r] + acc[mt2][0][r] + part[(pb + 0) * 64 + l];
                    float z1 = pz[mt2][1][r] + acc[mt2][1][r] + part[(pb + 4) * 64 + l];
                    float z2 = pz[mt2][2][r] + acc[mt2][2][r] + part[(pb + 8) * 64 + l];
                    float z3 = pz[mt2][3][r] + acc[mt2][3][r] + part[(pb + 12) * 64 + l];
                    float ig = sigf(z0);
                    float fg = sigf(z1);
                    float gg = tanhfast(z2);
                    float og = sigf(z3);
                    float cn = fg * creg[q] + ig * gg;
                    float hn = og * tanhfast(cn);
                    bool mk = mv[q] != 0;
                    float ho = mk ? hn : hprev[q];
                    creg[q] = mk ? cn : creg[q];
                    hprev[q] = ho;
                    xoutT[((size_t)s * DQ + j) * 64 + b] = ho;
                    unsigned hi = f2bf(ho);
                    unsigned lo = f2bf(ho - bf2f(hi));
                    size_t wi = (((size_t)(mh * 2 + mt2) * 16 + ktW) * 64 +
                                 (laneW_hi + lh * 4 + r)) * 8 + (u & 7);
                    store_short_coh(hwH + wi, hi);
                    store_short_coh(hwL + wi, lo);
                }
            }
        }

        // grid barrier: drain stores, symmetric flag poll
        __syncthreads();
        if (tid == 0)
            __hip_atomic_store(&bar[wg * 32], (unsigned)(sl + 1),
                               __ATOMIC_RELAXED, __HIP_MEMORY_SCOPE_AGENT);
        if (w == 0 && l < NWG) {
            while (__hip_atomic_load(&bar[l * 32], __ATOMIC_RELAXED,
                                     __HIP_MEMORY_SCOPE_AGENT) < (unsigned)(sl + 1))
                __builtin_amdgcn_s_sleep(1);
        }
        __syncthreads();
    }

    if (kh == 0) {
#pragma unroll
        for (int mt2 = 0; mt2 < 2; ++mt2)
#pragma unroll
            for (int r = 0; r < 4; ++r) {
                int b = mh * 32 + mt2 * 16 + lh * 4 + r;
                cT[j * 64 + b] = creg[mt2 * 4 + r];
                hT[j * 64 + b] = hprev[mt2 * 4 + r];
            }
    }
}

// ---------------- logits = x @ Wout + bout ----------------
__global__ __launch_bounds__(256) void k_out(const float* __restrict__ xT,
                                             const float* __restrict__ Wo,
                                             const float* __restrict__ bo,
                                             float* __restrict__ out) {
    __shared__ float WoL[64 * 64];
    int t = blockIdx.x;
    int tid = threadIdx.x;
    int b = tid & 63;
    int q = tid >> 6;
    float acc[16];
#pragma unroll
    for (int i = 0; i < 16; ++i) acc[i] = 0.f;

    for (int kc = 0; kc < 8; ++kc) {
        __syncthreads();
#pragma unroll
        for (int uu = 0; uu < 4; ++uu)
            *(float4*)&WoL[tid * 16 + uu * 4] =
                *(const float4*)&Wo[kc * 4096 + tid * 16 + uu * 4];
        __syncthreads();
        for (int kk = 0; kk < 64; ++kk) {
            float xv = xT[((size_t)t * DQ + kc * 64 + kk) * 64 + b];
#pragma unroll
            for (int uu = 0; uu < 4; ++uu) {
                float4 wv = *(const float4*)&WoL[kk * 64 + q * 16 + uu * 4];
                acc[uu * 4 + 0] += xv * wv.x;
                acc[uu * 4 + 1] += xv * wv.y;
                acc[uu * 4 + 2] += xv * wv.z;
                acc[uu * 4 + 3] += xv * wv.w;
            }
        }
    }
#pragma unroll
    for (int uu = 0; uu < 4; ++uu) {
        int n = q * 16 + uu * 4;
        float4 v = {acc[uu * 4 + 0] + bo[n + 0], acc[uu * 4 + 1] + bo[n + 1],
                    acc[uu * 4 + 2] + bo[n + 2], acc[uu * 4 + 3] + bo[n + 3]};
        *(float4*)&out[((size_t)(b * TQ + t)) * 64 + n] = v;
    }
}

extern "C" void kernel_launch(void* const* d_in, const int* in_sizes, int n_in,
                              void* d_out, int out_size, void* d_ws, size_t ws_size,
                              hipStream_t stream) {
    const int*   wid  = (const int*)d_in[0];
    const int*   pid  = (const int*)d_in[1];
    const int*   mask = (const int*)d_in[2];
    const float* emb  = (const float*)d_in[3];
    const float* Ws   = (const float*)d_in[4];
    const float* Us   = (const float*)d_in[5];
    const float* bs   = (const float*)d_in[6];
    const float* Wo   = (const float*)d_in[7];
    const float* bo   = (const float*)d_in[8];
    float* out = (float*)d_out;

    const size_t XN = (size_t)TQ * DQ * 64;       // 8388608 floats
    float* x0 = (float*)d_ws;
    float* x1 = x0 + XN;
    unsigned short* Ufh = (unsigned short*)(x1 + XN);   // 4 layers x 1M bf16
    unsigned short* Ufl = Ufh + 4194304;
    unsigned short* hf  = Ufl + 4194304;                // [2][2][32768]
    float* hT = (float*)(hf + 131072);
    float* cT = hT + 32768;
    unsigned* bar = (unsigned*)(cT + 32768);
    float* preF = (float*)((char*)bar + 8192);

    size_t base_bytes = (size_t)(2 * XN + 2 * 32768) * 4 + 4 * 4194304 + 131072 * 2 + 8192;
    int CHUNK = 256;
    while (CHUNK > 2 && base_bytes + (size_t)CHUNK * GQ * 64 * 4 > ws_size) CHUNK >>= 1;

    k_convU<<<16384, 256, 0, stream>>>(Us, Ufh, Ufl);
    k_embed<<<dim3(TQ, 8), 256, 0, stream>>>(wid, pid, emb, x0);

    float* xc = x0;
    float* xn = x1;
    for (int layer = 0; layer < 4; ++layer) {
        int flip = layer & 1;
        const float* W = Ws + (size_t)layer * DQ * GQ;
        const float* bias = bs + (size_t)layer * GQ;
        const unsigned short* Ufh_l = Ufh + (size_t)layer * 1048576;
        const unsigned short* Ufl_l = Ufl + (size_t)layer * 1048576;

        hipMemsetAsync(hf, 0, 131072, stream);               // parity-0 h frags
        hipMemsetAsync(hT, 0, 2 * 32768 * 4, stream);        // hT + cT
        for (int s0 = 0; s0 < TQ; s0 += CHUNK) {
            dim3 g(CHUNK, 32);
            k_pre<<<g, 256, 0, stream>>>(xc, W, bias, preF, s0, flip);
            hipMemsetAsync(bar, 0, 8192, stream);
            k_layer<<<NWG, 256, 0, stream>>>(Ufh_l, Ufl_l, preF, mask, hf, hT, cT,
                                             xn, bar, s0, CHUNK, flip);
        }
        float* t = xc; xc = xn; xn = t;
    }

    k_out<<<TQ, 256, 0, stream>>>(xc, Wo, bo, out);
}

// Round 5
// 8422.015 us; speedup vs baseline: 2.7345x; 2.7345x over previous
//
#include <hip/hip_runtime.h>
#include <math.h>

#define TQ 256
#define DQ 512
#define GQ 2048
#define NWG 32

typedef __attribute__((ext_vector_type(8))) short bf16x8;
typedef __attribute__((ext_vector_type(4))) float f32x4;

__device__ __forceinline__ unsigned f2bf(float x) {
    unsigned u = __builtin_bit_cast(unsigned, x);
    return (u + 0x7fffu + ((u >> 16) & 1u)) >> 16;
}
__device__ __forceinline__ float bf2f(unsigned s) {
    return __builtin_bit_cast(float, s << 16);
}
__device__ __forceinline__ float sigf(float x) { return 1.f / (1.f + __expf(-x)); }
__device__ __forceinline__ float tanhfast(float x) { return 1.f - 2.f / (__expf(2.f * x) + 1.f); }

// agent-coherent 16B load (reads at LLC, bypasses stale L1/L2)
__device__ __forceinline__ bf16x8 coh_load16(const unsigned short* p) {
    bf16x8 r;
    asm volatile("global_load_dwordx4 %0, %1, off sc0 sc1" : "=v"(r) : "v"(p));
    return r;
}
__device__ __forceinline__ void coh_store_short(unsigned short* p, unsigned v) {
    asm volatile("global_store_short %0, %1, off sc0 sc1" :: "v"(p), "v"(v));
}

// ---------------- embedding + predicate concat -> xT[t][d][b] ----------------
__global__ __launch_bounds__(256) void k_embed(const int* __restrict__ wid,
                                               const int* __restrict__ pid,
                                               const float* __restrict__ emb,
                                               float* __restrict__ xT) {
    __shared__ float Ls[64][65];
    int t = blockIdx.x;
    int d0 = blockIdx.y * 64;
    int tid = threadIdx.x;
    int l = tid & 63;
    int grp = tid >> 6;
#pragma unroll 4
    for (int bb = 0; bb < 16; ++bb) {
        int b = grp * 16 + bb;
        int d = d0 + l;
        float v;
        if (d < 511) v = emb[(size_t)wid[b * TQ + t] * 511 + d];
        else         v = (float)pid[b * TQ + t];
        Ls[l][b] = v;
    }
    __syncthreads();
#pragma unroll 4
    for (int dd = 0; dd < 16; ++dd) {
        int dl = grp * 16 + dd;
        xT[((size_t)t * DQ + d0 + dl) * 64 + l] = Ls[dl][l];
    }
}

// ---------------- U -> fragment-linear bf16 hi/lo (once, all layers) --------
__global__ __launch_bounds__(256) void k_convU(const float* __restrict__ Us,
                                               unsigned short* __restrict__ Ufh,
                                               unsigned short* __restrict__ Ufl) {
    int t = blockIdx.x * 256 + threadIdx.x;   // lay*2^20 + k*2048 + col
    int col = t & 2047;
    int k = (t >> 11) & 511;
    int lay = t >> 20;
    float v = Us[t];
    unsigned hi = f2bf(v);
    unsigned lo = f2bf(v - bf2f(hi));
    int g = col >> 9;
    int wgc = (col >> 4) & 31;
    int u = col & 15;
    int kt = k >> 5;
    int lane = ((k >> 3) & 3) * 16 + u;
    int jj = k & 7;
    size_t idx = (((((size_t)lay * NWG + wgc) * 4 + g) * 16 + kt) * 64 + lane) * 8 + jj;
    Ufh[idx] = (unsigned short)hi;
    Ufl[idx] = (unsigned short)lo;
}

// ---------------- preF[sl][wg][g][u][b] = xT(t_in) @ W + bias ----------------
__global__ __launch_bounds__(256) void k_pre(const float* __restrict__ xT,
                                             const float* __restrict__ W,
                                             const float* __restrict__ bias,
                                             float* __restrict__ preF,
                                             int s0, int flip) {
    __shared__ float As[16][68];   // [k][b]
    __shared__ float Bs[16][68];   // [k][n]
    int sl = blockIdx.x;
    int nt = blockIdx.y;
    int s = s0 + sl;
    int t_in = flip ? (TQ - 1 - s) : s;
    int tid = threadIdx.x;
    int tr = tid >> 4;              // 0..15 -> b quad
    int tc = tid & 15;              // 0..15 -> n quad
    int lk = tid >> 4;
    int lb4 = (tid & 15) * 4;

    float acc[4][4];
#pragma unroll
    for (int i = 0; i < 4; ++i)
#pragma unroll
        for (int jc = 0; jc < 4; ++jc) acc[i][jc] = 0.f;

    const float* xTt = xT + (size_t)t_in * DQ * 64;

    for (int kt = 0; kt < DQ; kt += 16) {
        *(float4*)&As[lk][lb4] = *(const float4*)&xTt[(size_t)(kt + lk) * 64 + lb4];
        *(float4*)&Bs[lk][lb4] = *(const float4*)&W[(size_t)(kt + lk) * GQ + nt * 64 + lb4];
        __syncthreads();
#pragma unroll
        for (int k = 0; k < 16; ++k) {
            float4 av = *(const float4*)&As[k][tr * 4];
            float4 bv = *(const float4*)&Bs[k][tc * 4];
            float a[4] = {av.x, av.y, av.z, av.w};
            float bb[4] = {bv.x, bv.y, bv.z, bv.w};
#pragma unroll
            for (int i = 0; i < 4; ++i)
#pragma unroll
                for (int jc = 0; jc < 4; ++jc) acc[i][jc] += a[i] * bb[jc];
        }
        __syncthreads();
    }
#pragma unroll
    for (int jc = 0; jc < 4; ++jc) {
        int col = nt * 64 + tc * 4 + jc;
        float bv = bias[col];
        int g = col >> 9;
        int wgc = (col >> 4) & 31;
        int uu = col & 15;
        float4 v = {acc[0][jc] + bv, acc[1][jc] + bv, acc[2][jc] + bv, acc[3][jc] + bv};
        *(float4*)&preF[((((size_t)sl * NWG + wgc) * 4 + g) * 16 + uu) * 64 + tr * 4] = v;
    }
}

// ---------------- persistent LSTM layer: reg-resident U, MFMA recurrence -----
// 32 WGs x 512 thr (8 waves). WG owns 16 units. wave: kh = w>>1 (k-quarter),
// mh = w&1 (batch half). U-hi frags in VGPRs; U-lo streamed from L2.
__global__ __launch_bounds__(512, 1) void k_layer(
    const unsigned short* __restrict__ Ufh,
    const unsigned short* __restrict__ Ufl,
    const float* __restrict__ preF,     // [sl][wg][g][u][b]
    const int* __restrict__ mask,
    unsigned short* __restrict__ hf,    // [parity][hi/lo][32768]
    float* __restrict__ hT,
    float* __restrict__ cT,
    float* __restrict__ xoutT,          // [s][j][b]
    unsigned* __restrict__ bar,
    int s0, int nsteps, int flip)
{
    __shared__ float part[6 * 8 * 64 * 4];   // 48 KB: [plane][mt2*4+g][l][r]

    int wg = blockIdx.x;
    int tid = threadIdx.x;
    int w = tid >> 6, l = tid & 63;
    int kh = w >> 1, mh = w & 1;
    int u = l & 15, lh = l >> 4;
    int j = wg * 16 + u;
    int ktW = wg >> 1;
    int laneW_hi = ((wg * 2 + (u >> 3)) & 3) * 16;

    // resident U-hi fragments for this wave's k-quarter
    bf16x8 BH[4][4];
#pragma unroll
    for (int kt2 = 0; kt2 < 4; ++kt2)
#pragma unroll
        for (int g = 0; g < 4; ++g)
            BH[kt2][g] = *(const bf16x8*)(Ufh +
                ((((size_t)wg * 4 + g) * 16 + kh * 4 + kt2) * 64 + l) * 8);

    float creg[8], hprev[8];
    if (kh == 0) {
#pragma unroll
        for (int mt2 = 0; mt2 < 2; ++mt2)
#pragma unroll
            for (int r = 0; r < 4; ++r) {
                int b = mh * 32 + mt2 * 16 + lh * 4 + r;
                creg[mt2 * 4 + r] = cT[j * 64 + b];
                hprev[mt2 * 4 + r] = hT[j * 64 + b];
            }
    }

    for (int sl = 0; sl < nsteps; ++sl) {
        int s = s0 + sl;
        int p = s & 1;
        const unsigned short* hrH = hf + ((size_t)p * 2 + 0) * 32768;
        const unsigned short* hrL = hf + ((size_t)p * 2 + 1) * 32768;
        unsigned short* hwH = hf + ((size_t)(p ^ 1) * 2 + 0) * 32768;
        unsigned short* hwL = hf + ((size_t)(p ^ 1) * 2 + 1) * 32768;

        // prefetch U-lo for kt2=0
        bf16x8 BL0[4], BL1[4];
#pragma unroll
        for (int g = 0; g < 4; ++g)
            BL0[g] = *(const bf16x8*)(Ufl +
                ((((size_t)wg * 4 + g) * 16 + kh * 4 + 0) * 64 + l) * 8);

        // acc init: finisher waves seed with pre (pz), others zero
        f32x4 acc[2][4];
        unsigned mvb = 0;
        if (kh == 0) {
            int t_in = flip ? (TQ - 1 - s) : s;
#pragma unroll
            for (int mt2 = 0; mt2 < 2; ++mt2)
#pragma unroll
                for (int g = 0; g < 4; ++g)
                    acc[mt2][g] = *(const f32x4*)&preF[
                        ((((size_t)sl * NWG + wg) * 4 + g) * 16 + u) * 64 +
                        mh * 32 + mt2 * 16 + lh * 4];
#pragma unroll
            for (int mt2 = 0; mt2 < 2; ++mt2)
#pragma unroll
                for (int r = 0; r < 4; ++r) {
                    int b = mh * 32 + mt2 * 16 + lh * 4 + r;
                    if (mask[b * TQ + (flip ? (TQ - 1 - s) : s)] != 0)
                        mvb |= 1u << (mt2 * 4 + r);
                }
        } else {
            f32x4 zv = {0.f, 0.f, 0.f, 0.f};
#pragma unroll
            for (int mt2 = 0; mt2 < 2; ++mt2)
#pragma unroll
                for (int g = 0; g < 4; ++g) acc[mt2][g] = zv;
        }

        // A (h) fragment loads: coherent 16B, all 16 in flight
        bf16x8 AH[2][4], AL[2][4];
#pragma unroll
        for (int mt2 = 0; mt2 < 2; ++mt2)
#pragma unroll
            for (int kt2 = 0; kt2 < 4; ++kt2) {
                int mt = mh * 2 + mt2;
                int kt = kh * 4 + kt2;
                AH[mt2][kt2] = coh_load16(hrH + ((size_t)(mt * 16 + kt) * 64 + l) * 8);
                AL[mt2][kt2] = coh_load16(hrL + ((size_t)(mt * 16 + kt) * 64 + l) * 8);
            }
        asm volatile("s_waitcnt vmcnt(0)");
        __builtin_amdgcn_sched_barrier(0);

        // MFMA: 3-term split-bf16, U-lo double-buffered
#pragma unroll
        for (int kt2 = 0; kt2 < 4; ++kt2) {
            bf16x8* BLc = (kt2 & 1) ? BL1 : BL0;
            bf16x8* BLn = (kt2 & 1) ? BL0 : BL1;
            if (kt2 < 3) {
#pragma unroll
                for (int g = 0; g < 4; ++g)
                    BLn[g] = *(const bf16x8*)(Ufl +
                        ((((size_t)wg * 4 + g) * 16 + kh * 4 + kt2 + 1) * 64 + l) * 8);
            }
#pragma unroll
            for (int g = 0; g < 4; ++g) {
                acc[0][g] = __builtin_amdgcn_mfma_f32_16x16x32_bf16(AH[0][kt2], BH[kt2][g], acc[0][g], 0, 0, 0);
                acc[1][g] = __builtin_amdgcn_mfma_f32_16x16x32_bf16(AH[1][kt2], BH[kt2][g], acc[1][g], 0, 0, 0);
                acc[0][g] = __builtin_amdgcn_mfma_f32_16x16x32_bf16(AL[0][kt2], BH[kt2][g], acc[0][g], 0, 0, 0);
                acc[1][g] = __builtin_amdgcn_mfma_f32_16x16x32_bf16(AL[1][kt2], BH[kt2][g], acc[1][g], 0, 0, 0);
                acc[0][g] = __builtin_amdgcn_mfma_f32_16x16x32_bf16(AH[0][kt2], BLc[g], acc[0][g], 0, 0, 0);
                acc[1][g] = __builtin_amdgcn_mfma_f32_16x16x32_bf16(AH[1][kt2], BLc[g], acc[1][g], 0, 0, 0);
            }
        }

        // cross-k reduction: kh 1..3 dump partials to LDS
        if (kh != 0) {
            int plane = (kh - 1) * 2 + mh;
#pragma unroll
            for (int mt2 = 0; mt2 < 2; ++mt2)
#pragma unroll
                for (int g = 0; g < 4; ++g)
                    *(f32x4*)&part[((size_t)(plane * 8 + mt2 * 4 + g) * 64 + l) * 4] = acc[mt2][g];
        }
        __syncthreads();

        if (kh == 0) {
#pragma unroll
            for (int mt2 = 0; mt2 < 2; ++mt2) {
                f32x4 zg[4];
#pragma unroll
                for (int g = 0; g < 4; ++g) {
                    zg[g] = acc[mt2][g];
#pragma unroll
                    for (int pp = 0; pp < 3; ++pp)
                        zg[g] += *(const f32x4*)&part[
                            ((size_t)((pp * 2 + mh) * 8 + mt2 * 4 + g) * 64 + l) * 4];
                }
#pragma unroll
                for (int r = 0; r < 4; ++r) {
                    int q = mt2 * 4 + r;
                    int b = mh * 32 + mt2 * 16 + lh * 4 + r;
                    float ig = sigf(zg[0][r]);
                    float fg = sigf(zg[1][r]);
                    float gg = tanhfast(zg[2][r]);
                    float og = sigf(zg[3][r]);
                    float cn = fg * creg[q] + ig * gg;
                    float hn = og * tanhfast(cn);
                    bool mk = (mvb >> q) & 1u;
                    float ho = mk ? hn : hprev[q];
                    creg[q] = mk ? cn : creg[q];
                    hprev[q] = ho;
                    xoutT[((size_t)s * DQ + j) * 64 + b] = ho;
                    unsigned hi = f2bf(ho);
                    unsigned lo = f2bf(ho - bf2f(hi));
                    size_t wi = (((size_t)(mh * 2 + mt2) * 16 + ktW) * 64 +
                                 (laneW_hi + lh * 4 + r)) * 8 + (u & 7);
                    coh_store_short(hwH + wi, hi);
                    coh_store_short(hwL + wi, lo);
                }
            }
            asm volatile("s_waitcnt vmcnt(0)" ::: "memory");
        }

        // grid barrier: symmetric flag poll
        __syncthreads();
        if (tid == 0)
            __hip_atomic_store(&bar[wg * 32], (unsigned)(sl + 1),
                               __ATOMIC_RELAXED, __HIP_MEMORY_SCOPE_AGENT);
        if (w == 0 && l < NWG) {
            while (__hip_atomic_load(&bar[l * 32], __ATOMIC_RELAXED,
                                     __HIP_MEMORY_SCOPE_AGENT) < (unsigned)(sl + 1))
                __builtin_amdgcn_s_sleep(1);
        }
        __syncthreads();
    }

    if (kh == 0) {
#pragma unroll
        for (int mt2 = 0; mt2 < 2; ++mt2)
#pragma unroll
            for (int r = 0; r < 4; ++r) {
                int b = mh * 32 + mt2 * 16 + lh * 4 + r;
                cT[j * 64 + b] = creg[mt2 * 4 + r];
                hT[j * 64 + b] = hprev[mt2 * 4 + r];
            }
    }
}

// ---------------- logits = x @ Wout + bout ----------------
__global__ __launch_bounds__(256) void k_out(const float* __restrict__ xT,
                                             const float* __restrict__ Wo,
                                             const float* __restrict__ bo,
                                             float* __restrict__ out) {
    __shared__ float WoL[64 * 64];
    int t = blockIdx.x;
    int tid = threadIdx.x;
    int b = tid & 63;
    int q = tid >> 6;
    float acc[16];
#pragma unroll
    for (int i = 0; i < 16; ++i) acc[i] = 0.f;

    for (int kc = 0; kc < 8; ++kc) {
        __syncthreads();
#pragma unroll
        for (int uu = 0; uu < 4; ++uu)
            *(float4*)&WoL[tid * 16 + uu * 4] =
                *(const float4*)&Wo[kc * 4096 + tid * 16 + uu * 4];
        __syncthreads();
        for (int kk = 0; kk < 64; ++kk) {
            float xv = xT[((size_t)t * DQ + kc * 64 + kk) * 64 + b];
#pragma unroll
            for (int uu = 0; uu < 4; ++uu) {
                float4 wv = *(const float4*)&WoL[kk * 64 + q * 16 + uu * 4];
                acc[uu * 4 + 0] += xv * wv.x;
                acc[uu * 4 + 1] += xv * wv.y;
                acc[uu * 4 + 2] += xv * wv.z;
                acc[uu * 4 + 3] += xv * wv.w;
            }
        }
    }
#pragma unroll
    for (int uu = 0; uu < 4; ++uu) {
        int n = q * 16 + uu * 4;
        float4 v = {acc[uu * 4 + 0] + bo[n + 0], acc[uu * 4 + 1] + bo[n + 1],
                    acc[uu * 4 + 2] + bo[n + 2], acc[uu * 4 + 3] + bo[n + 3]};
        *(float4*)&out[((size_t)(b * TQ + t)) * 64 + n] = v;
    }
}

extern "C" void kernel_launch(void* const* d_in, const int* in_sizes, int n_in,
                              void* d_out, int out_size, void* d_ws, size_t ws_size,
                              hipStream_t stream) {
    const int*   wid  = (const int*)d_in[0];
    const int*   pid  = (const int*)d_in[1];
    const int*   mask = (const int*)d_in[2];
    const float* emb  = (const float*)d_in[3];
    const float* Ws   = (const float*)d_in[4];
    const float* Us   = (const float*)d_in[5];
    const float* bs   = (const float*)d_in[6];
    const float* Wo   = (const float*)d_in[7];
    const float* bo   = (const float*)d_in[8];
    float* out = (float*)d_out;

    const size_t XN = (size_t)TQ * DQ * 64;       // 8388608 floats
    float* x0 = (float*)d_ws;
    float* x1 = x0 + XN;
    unsigned short* Ufh = (unsigned short*)(x1 + XN);   // 4 layers x 1M bf16
    unsigned short* Ufl = Ufh + 4194304;
    unsigned short* hf  = Ufl + 4194304;                // [2][2][32768]
    float* hT = (float*)(hf + 131072);
    float* cT = hT + 32768;
    unsigned* bar = (unsigned*)(cT + 32768);
    float* preF = (float*)((char*)bar + 8192);

    size_t base_bytes = (size_t)(2 * XN + 2 * 32768) * 4 + 4 * 4194304 + 131072 * 2 + 8192;
    int CHUNK = 256;
    while (CHUNK > 2 && base_bytes + (size_t)CHUNK * GQ * 64 * 4 > ws_size) CHUNK >>= 1;

    k_convU<<<16384, 256, 0, stream>>>(Us, Ufh, Ufl);
    k_embed<<<dim3(TQ, 8), 256, 0, stream>>>(wid, pid, emb, x0);

    float* xc = x0;
    float* xn = x1;
    for (int layer = 0; layer < 4; ++layer) {
        int flip = layer & 1;
        const float* W = Ws + (size_t)layer * DQ * GQ;
        const float* bias = bs + (size_t)layer * GQ;
        const unsigned short* Ufh_l = Ufh + (size_t)layer * 1048576;
        const unsigned short* Ufl_l = Ufl + (size_t)layer * 1048576;

        hipMemsetAsync(hf, 0, 131072, stream);               // parity-0 h frags
        hipMemsetAsync(hT, 0, 2 * 32768 * 4, stream);        // hT + cT
        for (int s0 = 0; s0 < TQ; s0 += CHUNK) {
            dim3 g(CHUNK, 32);
            k_pre<<<g, 256, 0, stream>>>(xc, W, bias, preF, s0, flip);
            hipMemsetAsync(bar, 0, 8192, stream);
            k_layer<<<NWG, 512, 0, stream>>>(Ufh_l, Ufl_l, preF, mask, hf, hT, cT,
                                             xn, bar, s0, CHUNK, flip);
        }
        float* t = xc; xc = xn; xn = t;
    }

    k_out<<<TQ, 256, 0, stream>>>(xc, Wo, bo, out);
}

// Round 6
// 4736.877 us; speedup vs baseline: 4.8619x; 1.7780x over previous
//
#include <hip/hip_runtime.h>
#include <math.h>

#define TQ 256
#define DQ 512
#define GQ 2048
#define LWG 64

typedef __attribute__((ext_vector_type(8))) short bf16x8;
typedef __attribute__((ext_vector_type(4))) float f32x4;

__device__ __forceinline__ unsigned f2bf(float x) {
    unsigned u = __builtin_bit_cast(unsigned, x);
    return (u + 0x7fffu + ((u >> 16) & 1u)) >> 16;
}
__device__ __forceinline__ float bf2f(unsigned s) {
    return __builtin_bit_cast(float, s << 16);
}
__device__ __forceinline__ float sigf(float x) { return 1.f / (1.f + __expf(-x)); }
__device__ __forceinline__ float tanhfast(float x) { return 1.f - 2.f / (__expf(2.f * x) + 1.f); }

__device__ __forceinline__ bf16x8 coh_load16(const unsigned short* p) {
    bf16x8 r;
    asm volatile("global_load_dwordx4 %0, %1, off sc0 sc1" : "=v"(r) : "v"(p));
    return r;
}
__device__ __forceinline__ void coh_store_short(unsigned short* p, unsigned v) {
    asm volatile("global_store_short %0, %1, off sc0 sc1" :: "v"(p), "v"(v));
}

// ---------------- embedding + predicate concat -> xRaw[t][d][b] --------------
__global__ __launch_bounds__(256) void k_embed(const int* __restrict__ wid,
                                               const int* __restrict__ pid,
                                               const float* __restrict__ emb,
                                               float* __restrict__ xT) {
    __shared__ float Ls[64][65];
    int t = blockIdx.x;
    int d0 = blockIdx.y * 64;
    int tid = threadIdx.x;
    int l = tid & 63;
    int grp = tid >> 6;
#pragma unroll 4
    for (int bb = 0; bb < 16; ++bb) {
        int b = grp * 16 + bb;
        int d = d0 + l;
        float v;
        if (d < 511) v = emb[(size_t)wid[b * TQ + t] * 511 + d];
        else         v = (float)pid[b * TQ + t];
        Ls[l][b] = v;
    }
    __syncthreads();
#pragma unroll 4
    for (int dd = 0; dd < 16; ++dd) {
        int dl = grp * 16 + dd;
        xT[((size_t)t * DQ + d0 + dl) * 64 + l] = Ls[dl][l];
    }
}

// ---------------- xRaw -> x fragments (layer-0 input) ------------------------
// frag element (b,k): frame F: ((F*4 + (b>>4))*16 + (k>>5))*512 + (((k>>3)&3)*16 + (b&15))*8 + (k&7)
__global__ __launch_bounds__(256) void k_convX(const float* __restrict__ xT,
                                               unsigned short* __restrict__ Xh,
                                               unsigned short* __restrict__ Xl) {
    int idx = blockIdx.x * 256 + threadIdx.x;    // (t*512 + d)*64 + b
    int b = idx & 63;
    int d = (idx >> 6) & 511;
    int t = idx >> 15;
    float v = xT[idx];
    unsigned hi = f2bf(v);
    unsigned lo = f2bf(v - bf2f(hi));
    size_t wi = (((size_t)(1 + t) * 4 + (b >> 4)) * 16 + (d >> 5)) * 512 +
                (((d >> 3) & 3) * 16 + (b & 15)) * 8 + (d & 7);
    Xh[wi] = (unsigned short)hi;
    Xl[wi] = (unsigned short)lo;
}

// ---------------- W -> A-operand fragments (m = col) -------------------------
__global__ __launch_bounds__(256) void k_convW(const float* __restrict__ Ws,
                                               unsigned short* __restrict__ Wh,
                                               unsigned short* __restrict__ Wl) {
    int idx = blockIdx.x * 256 + threadIdx.x;    // (lay*512 + d)*2048 + c
    int c = idx & 2047;
    int d = (idx >> 11) & 511;
    int lay = idx >> 20;
    float v = Ws[idx];
    unsigned hi = f2bf(v);
    unsigned lo = f2bf(v - bf2f(hi));
    size_t wi = (((size_t)lay * 128 + (c >> 4)) * 16 + (d >> 5)) * 512 +
                (((d >> 3) & 3) * 16 + (c & 15)) * 8 + (d & 7);
    Wh[wi] = (unsigned short)hi;
    Wl[wi] = (unsigned short)lo;
}

// ---------------- U -> B-operand fragments (n = (g&1)*8 + j) -----------------
__global__ __launch_bounds__(256) void k_convU(const float* __restrict__ Us,
                                               unsigned short* __restrict__ Uh,
                                               unsigned short* __restrict__ Ul) {
    int idx = blockIdx.x * 256 + threadIdx.x;    // (lay*512 + k)*2048 + c
    int c = idx & 2047;
    int k = (idx >> 11) & 511;
    int lay = idx >> 20;
    float v = Us[idx];
    unsigned hi = f2bf(v);
    unsigned lo = f2bf(v - bf2f(hi));
    int g = c >> 9;
    int wgc = (c >> 3) & 63;
    int jl = c & 7;
    int nt = g >> 1;
    int n = (g & 1) * 8 + jl;
    size_t wi = ((((size_t)lay * LWG + wgc) * 16 + (k >> 5)) * 2 + nt) * 512 +
                (((k >> 3) & 3) * 16 + n) * 8 + (k & 7);
    Uh[wi] = (unsigned short)hi;
    Ul[wi] = (unsigned short)lo;
}

// ---------------- pre = x @ W + bias  (MFMA, 3-term split-bf16) --------------
// grid (CHUNK, 16). WG: one s, 128 cols. 4 waves, wave w: ct = cg*8 + w*2 + cc.
// preF layout: [sl][c][b]
__global__ __launch_bounds__(256) void k_preM(const unsigned short* __restrict__ Wh,
                                              const unsigned short* __restrict__ Wl,
                                              const unsigned short* __restrict__ Xh,
                                              const unsigned short* __restrict__ Xl,
                                              const float* __restrict__ bias,
                                              float* __restrict__ preF,
                                              int s0, int flip) {
    int sl = blockIdx.x;
    int cg = blockIdx.y;
    int s = s0 + sl;
    int t_in = flip ? (TQ - 1 - s) : s;
    int tid = threadIdx.x;
    int w = tid >> 6, l = tid & 63;

    f32x4 acc[2][4];
    f32x4 zv = {0.f, 0.f, 0.f, 0.f};
#pragma unroll
    for (int cc = 0; cc < 2; ++cc)
#pragma unroll
        for (int bt = 0; bt < 4; ++bt) acc[cc][bt] = zv;

    size_t xb = (size_t)(1 + t_in) * (4 * 16 * 512);

#pragma unroll 2
    for (int kt = 0; kt < 16; ++kt) {
        bf16x8 ah[2], al[2], bh[4], bl[4];
#pragma unroll
        for (int cc = 0; cc < 2; ++cc) {
            size_t a = ((size_t)(cg * 8 + w * 2 + cc) * 16 + kt) * 512 + l * 8;
            ah[cc] = *(const bf16x8*)(Wh + a);
            al[cc] = *(const bf16x8*)(Wl + a);
        }
#pragma unroll
        for (int bt = 0; bt < 4; ++bt) {
            size_t a = xb + ((size_t)(bt * 16 + kt)) * 512 + l * 8;
            bh[bt] = *(const bf16x8*)(Xh + a);
            bl[bt] = *(const bf16x8*)(Xl + a);
        }
#pragma unroll
        for (int cc = 0; cc < 2; ++cc)
#pragma unroll
            for (int bt = 0; bt < 4; ++bt) {
                acc[cc][bt] = __builtin_amdgcn_mfma_f32_16x16x32_bf16(ah[cc], bh[bt], acc[cc][bt], 0, 0, 0);
                acc[cc][bt] = __builtin_amdgcn_mfma_f32_16x16x32_bf16(al[cc], bh[bt], acc[cc][bt], 0, 0, 0);
                acc[cc][bt] = __builtin_amdgcn_mfma_f32_16x16x32_bf16(ah[cc], bl[bt], acc[cc][bt], 0, 0, 0);
            }
    }

#pragma unroll
    for (int cc = 0; cc < 2; ++cc) {
        int ctg = cg * 8 + w * 2 + cc;
#pragma unroll
        for (int r = 0; r < 4; ++r) {
            int c = ctg * 16 + (l >> 4) * 4 + r;
            float bv = bias[c];
#pragma unroll
            for (int bt = 0; bt < 4; ++bt)
                preF[((size_t)sl * GQ + c) * 64 + bt * 16 + (l & 15)] = acc[cc][bt][r] + bv;
        }
    }
}

// ---------------- persistent LSTM layer ----------------
// 64 WGs x 512 thr. WG owns 8 units. wave w: kh=w>>1 (k-quarter), mh=w&1.
// U hi+lo register-resident. finish: thread -> (j = tid>>6, b = tid&63).
__global__ __launch_bounds__(512, 1) void k_layer(
    const unsigned short* __restrict__ Uh,
    const unsigned short* __restrict__ Ul,
    const float* __restrict__ preF,     // [sl][c][b]
    const int* __restrict__ mask,
    unsigned short* __restrict__ Xh,    // exchange + next-layer x frags
    unsigned short* __restrict__ Xl,
    float* __restrict__ xT32,           // [s][j][b] fp32 (for k_out)
    float* __restrict__ cT,
    float* __restrict__ hT,
    unsigned* __restrict__ bar,
    int s0, int nsteps, int flip)
{
    __shared__ float part[128 * 65];    // [ (kh*2+nt)*16 + n ][ b ], pad 65

    int wg = blockIdx.x;
    int tid = threadIdx.x;
    int w = tid >> 6, l = tid & 63;
    int kh = w >> 1, mh = w & 1;
    int jglob = wg * 8 + w;

    // resident U fragments (hi + lo) for this wave's k-quarter
    bf16x8 BH[4][2], BL[4][2];
#pragma unroll
    for (int kt2 = 0; kt2 < 4; ++kt2)
#pragma unroll
        for (int nt = 0; nt < 2; ++nt) {
            size_t a = (((size_t)wg * 16 + (kh * 4 + kt2)) * 2 + nt) * 512 + l * 8;
            BH[kt2][nt] = *(const bf16x8*)(Uh + a);
            BL[kt2][nt] = *(const bf16x8*)(Ul + a);
        }

    float creg = cT[(size_t)jglob * 64 + l];
    float hpre = hT[(size_t)jglob * 64 + l];

    // prefetch finish operands for first step
    float pzv[4];
    int maskv;
    {
        int t0 = flip ? (TQ - 1 - s0) : s0;
        maskv = mask[l * TQ + t0];
#pragma unroll
        for (int g = 0; g < 4; ++g)
            pzv[g] = preF[((size_t)(g * 512 + wg * 8 + w)) * 64 + l];
    }

    for (int sl = 0; sl < nsteps; ++sl) {
        int s = s0 + sl;

        // A (h) fragment loads: coherent 16B
        bf16x8 AH[2][4], AL[2][4];
        size_t fb = (size_t)s * (4 * 16 * 512);
#pragma unroll
        for (int mt2 = 0; mt2 < 2; ++mt2)
#pragma unroll
            for (int kt2 = 0; kt2 < 4; ++kt2) {
                int mt = mh * 2 + mt2;
                int kt = kh * 4 + kt2;
                size_t a = fb + ((size_t)(mt * 16 + kt)) * 512 + (size_t)l * 8;
                AH[mt2][kt2] = coh_load16(Xh + a);
                AL[mt2][kt2] = coh_load16(Xl + a);
            }
        asm volatile("s_waitcnt vmcnt(0)" ::: "memory");
        __builtin_amdgcn_sched_barrier(0);

        f32x4 acc[2][2];
        f32x4 zv = {0.f, 0.f, 0.f, 0.f};
#pragma unroll
        for (int mt2 = 0; mt2 < 2; ++mt2)
#pragma unroll
            for (int nt = 0; nt < 2; ++nt) acc[mt2][nt] = zv;

#pragma unroll
        for (int kt2 = 0; kt2 < 4; ++kt2)
#pragma unroll
            for (int nt = 0; nt < 2; ++nt) {
                acc[0][nt] = __builtin_amdgcn_mfma_f32_16x16x32_bf16(AH[0][kt2], BH[kt2][nt], acc[0][nt], 0, 0, 0);
                acc[1][nt] = __builtin_amdgcn_mfma_f32_16x16x32_bf16(AH[1][kt2], BH[kt2][nt], acc[1][nt], 0, 0, 0);
                acc[0][nt] = __builtin_amdgcn_mfma_f32_16x16x32_bf16(AL[0][kt2], BH[kt2][nt], acc[0][nt], 0, 0, 0);
                acc[1][nt] = __builtin_amdgcn_mfma_f32_16x16x32_bf16(AL[1][kt2], BH[kt2][nt], acc[1][nt], 0, 0, 0);
                acc[0][nt] = __builtin_amdgcn_mfma_f32_16x16x32_bf16(AH[0][kt2], BL[kt2][nt], acc[0][nt], 0, 0, 0);
                acc[1][nt] = __builtin_amdgcn_mfma_f32_16x16x32_bf16(AH[1][kt2], BL[kt2][nt], acc[1][nt], 0, 0, 0);
            }

        // dump partials
#pragma unroll
        for (int mt2 = 0; mt2 < 2; ++mt2)
#pragma unroll
            for (int nt = 0; nt < 2; ++nt)
#pragma unroll
                for (int r = 0; r < 4; ++r)
                    part[((kh * 2 + nt) * 16 + (l & 15)) * 65 +
                         (mh * 32 + mt2 * 16 + (l >> 4) * 4 + r)] = acc[mt2][nt][r];
        __syncthreads();

        // balanced finish: this thread owns (j = w, b = l)
        float z[4];
#pragma unroll
        for (int g = 0; g < 4; ++g) {
            float zz = pzv[g];
#pragma unroll
            for (int k2 = 0; k2 < 4; ++k2)
                zz += part[((k2 * 2 + (g >> 1)) * 16 + ((g & 1) * 8 + w)) * 65 + l];
            z[g] = zz;
        }
        float ig = sigf(z[0]);
        float fg = sigf(z[1]);
        float gg = tanhfast(z[2]);
        float og = sigf(z[3]);
        float cn = fg * creg + ig * gg;
        float hn = og * tanhfast(cn);
        bool mk = maskv != 0;
        float ho = mk ? hn : hpre;
        creg = mk ? cn : creg;
        hpre = ho;

        xT32[((size_t)s * DQ + jglob) * 64 + l] = ho;
        unsigned hi = f2bf(ho);
        unsigned lo = f2bf(ho - bf2f(hi));
        size_t wi = (((size_t)(s + 1) * 4 + (l >> 4)) * 16 + (jglob >> 5)) * 512 +
                    (((jglob >> 3) & 3) * 16 + (l & 15)) * 8 + (jglob & 7);
        coh_store_short(Xh + wi, hi);
        coh_store_short(Xl + wi, lo);

        // prefetch next step's finish operands
        if (sl + 1 < nsteps) {
            int t1 = flip ? (TQ - 1 - (s + 1)) : (s + 1);
            maskv = mask[l * TQ + t1];
#pragma unroll
            for (int g = 0; g < 4; ++g)
                pzv[g] = preF[((size_t)(sl + 1) * GQ + g * 512 + wg * 8 + w) * 64 + l];
        }

        // drain stores, grid barrier (symmetric flag poll)
        asm volatile("s_waitcnt vmcnt(0)" ::: "memory");
        __syncthreads();
        if (tid == 0)
            __hip_atomic_store(&bar[wg * 16], (unsigned)(sl + 1),
                               __ATOMIC_RELAXED, __HIP_MEMORY_SCOPE_AGENT);
        if (w == 0) {
            while (__hip_atomic_load(&bar[l * 16], __ATOMIC_RELAXED,
                                     __HIP_MEMORY_SCOPE_AGENT) < (unsigned)(sl + 1))
                __builtin_amdgcn_s_sleep(1);
        }
        __syncthreads();
    }

    cT[(size_t)jglob * 64 + l] = creg;
    hT[(size_t)jglob * 64 + l] = hpre;
}

// ---------------- logits = x @ Wout + bout ----------------
__global__ __launch_bounds__(256) void k_out(const float* __restrict__ xT,
                                             const float* __restrict__ Wo,
                                             const float* __restrict__ bo,
                                             float* __restrict__ out) {
    __shared__ float WoL[64 * 64];
    int t = blockIdx.x;
    int tid = threadIdx.x;
    int b = tid & 63;
    int q = tid >> 6;
    float acc[16];
#pragma unroll
    for (int i = 0; i < 16; ++i) acc[i] = 0.f;

    for (int kc = 0; kc < 8; ++kc) {
        __syncthreads();
#pragma unroll
        for (int uu = 0; uu < 4; ++uu)
            *(float4*)&WoL[tid * 16 + uu * 4] =
                *(const float4*)&Wo[kc * 4096 + tid * 16 + uu * 4];
        __syncthreads();
        for (int kk = 0; kk < 64; ++kk) {
            float xv = xT[((size_t)t * DQ + kc * 64 + kk) * 64 + b];
#pragma unroll
            for (int uu = 0; uu < 4; ++uu) {
                float4 wv = *(const float4*)&WoL[kk * 64 + q * 16 + uu * 4];
                acc[uu * 4 + 0] += xv * wv.x;
                acc[uu * 4 + 1] += xv * wv.y;
                acc[uu * 4 + 2] += xv * wv.z;
                acc[uu * 4 + 3] += xv * wv.w;
            }
        }
    }
#pragma unroll
    for (int uu = 0; uu < 4; ++uu) {
        int n = q * 16 + uu * 4;
        float4 v = {acc[uu * 4 + 0] + bo[n + 0], acc[uu * 4 + 1] + bo[n + 1],
                    acc[uu * 4 + 2] + bo[n + 2], acc[uu * 4 + 3] + bo[n + 3]};
        *(float4*)&out[((size_t)(b * TQ + t)) * 64 + n] = v;
    }
}

extern "C" void kernel_launch(void* const* d_in, const int* in_sizes, int n_in,
                              void* d_out, int out_size, void* d_ws, size_t ws_size,
                              hipStream_t stream) {
    const int*   wid  = (const int*)d_in[0];
    const int*   pid  = (const int*)d_in[1];
    const int*   mask = (const int*)d_in[2];
    const float* emb  = (const float*)d_in[3];
    const float* Ws   = (const float*)d_in[4];
    const float* Us   = (const float*)d_in[5];
    const float* bs   = (const float*)d_in[6];
    const float* Wo   = (const float*)d_in[7];
    const float* bo   = (const float*)d_in[8];
    float* out = (float*)d_out;

    const size_t XFPLANE = (size_t)257 * 32768;      // shorts per plane
    char* p = (char*)d_ws;
    float* xRaw = (float*)p;                 p += 33554432;   // fp32 x / xT32
    unsigned short* XFA = (unsigned short*)p; p += 2 * XFPLANE * 2;
    unsigned short* XFB = (unsigned short*)p; p += 2 * XFPLANE * 2;
    unsigned short* UFh = (unsigned short*)p; p += 8388608;
    unsigned short* UFl = (unsigned short*)p; p += 8388608;
    unsigned short* WFh = (unsigned short*)p; p += 8388608;
    unsigned short* WFl = (unsigned short*)p; p += 8388608;
    float* cT = (float*)p;                   p += 131072;
    float* hT = (float*)p;                   p += 131072;
    unsigned* bar = (unsigned*)p;            p += 4096;
    float* preF = (float*)p;

    size_t base_bytes = (size_t)(p - (char*)d_ws);
    int CHUNK = 256;
    while (CHUNK > 2 && base_bytes + (size_t)CHUNK * GQ * 64 * 4 > ws_size) CHUNK >>= 1;

    k_convU<<<16384, 256, 0, stream>>>(Us, UFh, UFl);
    k_convW<<<16384, 256, 0, stream>>>(Ws, WFh, WFl);
    k_embed<<<dim3(TQ, 8), 256, 0, stream>>>(wid, pid, emb, xRaw);
    k_convX<<<32768, 256, 0, stream>>>(xRaw, XFA, XFA + XFPLANE);

    for (int layer = 0; layer < 4; ++layer) {
        int flip = layer & 1;
        const float* bias = bs + (size_t)layer * GQ;
        const unsigned short* UFh_l = UFh + (size_t)layer * 1048576;
        const unsigned short* UFl_l = UFl + (size_t)layer * 1048576;
        const unsigned short* WFh_l = WFh + (size_t)layer * 1048576;
        const unsigned short* WFl_l = WFl + (size_t)layer * 1048576;
        unsigned short* Xi = (layer & 1) ? XFB : XFA;
        unsigned short* Xo = (layer & 1) ? XFA : XFB;

        hipMemsetAsync(cT, 0, 262144, stream);                 // cT + hT
        hipMemsetAsync(Xo, 0, 65536, stream);                  // frame 0 hi
        hipMemsetAsync(Xo + XFPLANE, 0, 65536, stream);        // frame 0 lo

        for (int s0 = 0; s0 < TQ; s0 += CHUNK) {
            dim3 g(CHUNK, 16);
            k_preM<<<g, 256, 0, stream>>>(WFh_l, WFl_l, Xi, Xi + XFPLANE,
                                          bias, preF, s0, flip);
            hipMemsetAsync(bar, 0, 4096, stream);
            k_layer<<<LWG, 512, 0, stream>>>(UFh_l, UFl_l, preF, mask,
                                             Xo, Xo + XFPLANE, xRaw, cT, hT, bar,
                                             s0, CHUNK, flip);
        }
    }

    k_out<<<TQ, 256, 0, stream>>>(xRaw, Wo, bo, out);
}

// Round 7
// 4260.263 us; speedup vs baseline: 5.4058x; 1.1119x over previous
//
#include <hip/hip_runtime.h>
#include <math.h>

#define TQ 256
#define DQ 512
#define GQ 2048
#define LWG 64

typedef __attribute__((ext_vector_type(8))) short bf16x8;
typedef __attribute__((ext_vector_type(4))) float f32x4;
typedef __attribute__((ext_vector_type(4))) unsigned u32x4;

__device__ __forceinline__ unsigned f2bf(float x) {
    unsigned u = __builtin_bit_cast(unsigned, x);
    return (u + 0x7fffu + ((u >> 16) & 1u)) >> 16;
}
__device__ __forceinline__ float bf2f(unsigned s) {
    return __builtin_bit_cast(float, s << 16);
}
__device__ __forceinline__ float sigf(float x) { return 1.f / (1.f + __expf(-x)); }
__device__ __forceinline__ float tanhfast(float x) { return 1.f - 2.f / (__expf(2.f * x) + 1.f); }

// L1-bypass load (L2-coherent within XCD; frames are write-once so L2 fills are fresh)
__device__ __forceinline__ bf16x8 frag_load16(const unsigned short* p) {
    bf16x8 r;
    asm volatile("global_load_dwordx4 %0, %1, off sc0" : "=v"(r) : "v"(p));
    return r;
}

// ---------------- embedding + predicate concat -> xRaw[t][d][b] --------------
__global__ __launch_bounds__(256) void k_embed(const int* __restrict__ wid,
                                               const int* __restrict__ pid,
                                               const float* __restrict__ emb,
                                               float* __restrict__ xT) {
    __shared__ float Ls[64][65];
    int t = blockIdx.x;
    int d0 = blockIdx.y * 64;
    int tid = threadIdx.x;
    int l = tid & 63;
    int grp = tid >> 6;
#pragma unroll 4
    for (int bb = 0; bb < 16; ++bb) {
        int b = grp * 16 + bb;
        int d = d0 + l;
        float v;
        if (d < 511) v = emb[(size_t)wid[b * TQ + t] * 511 + d];
        else         v = (float)pid[b * TQ + t];
        Ls[l][b] = v;
    }
    __syncthreads();
#pragma unroll 4
    for (int dd = 0; dd < 16; ++dd) {
        int dl = grp * 16 + dd;
        xT[((size_t)t * DQ + d0 + dl) * 64 + l] = Ls[dl][l];
    }
}

// ---------------- xRaw -> x fragments (layer-0 input) ------------------------
__global__ __launch_bounds__(256) void k_convX(const float* __restrict__ xT,
                                               unsigned short* __restrict__ Xh,
                                               unsigned short* __restrict__ Xl) {
    int idx = blockIdx.x * 256 + threadIdx.x;    // (t*512 + d)*64 + b
    int b = idx & 63;
    int d = (idx >> 6) & 511;
    int t = idx >> 15;
    float v = xT[idx];
    unsigned hi = f2bf(v);
    unsigned lo = f2bf(v - bf2f(hi));
    size_t wi = (((size_t)(1 + t) * 4 + (b >> 4)) * 16 + (d >> 5)) * 512 +
                (((d >> 3) & 3) * 16 + (b & 15)) * 8 + (d & 7);
    Xh[wi] = (unsigned short)hi;
    Xl[wi] = (unsigned short)lo;
}

// ---------------- W -> A-operand fragments (m = col) -------------------------
__global__ __launch_bounds__(256) void k_convW(const float* __restrict__ Ws,
                                               unsigned short* __restrict__ Wh,
                                               unsigned short* __restrict__ Wl) {
    int idx = blockIdx.x * 256 + threadIdx.x;    // (lay*512 + d)*2048 + c
    int c = idx & 2047;
    int d = (idx >> 11) & 511;
    int lay = idx >> 20;
    float v = Ws[idx];
    unsigned hi = f2bf(v);
    unsigned lo = f2bf(v - bf2f(hi));
    size_t wi = (((size_t)lay * 128 + (c >> 4)) * 16 + (d >> 5)) * 512 +
                (((d >> 3) & 3) * 16 + (c & 15)) * 8 + (d & 7);
    Wh[wi] = (unsigned short)hi;
    Wl[wi] = (unsigned short)lo;
}

// ---------------- U -> B-operand fragments (n = (g&1)*8 + j) -----------------
__global__ __launch_bounds__(256) void k_convU(const float* __restrict__ Us,
                                               unsigned short* __restrict__ Uh,
                                               unsigned short* __restrict__ Ul) {
    int idx = blockIdx.x * 256 + threadIdx.x;    // (lay*512 + k)*2048 + c
    int c = idx & 2047;
    int k = (idx >> 11) & 511;
    int lay = idx >> 20;
    float v = Us[idx];
    unsigned hi = f2bf(v);
    unsigned lo = f2bf(v - bf2f(hi));
    int g = c >> 9;
    int wgc = (c >> 3) & 63;
    int jl = c & 7;
    int nt = g >> 1;
    int n = (g & 1) * 8 + jl;
    size_t wi = ((((size_t)lay * LWG + wgc) * 16 + (k >> 5)) * 2 + nt) * 512 +
                (((k >> 3) & 3) * 16 + n) * 8 + (k & 7);
    Uh[wi] = (unsigned short)hi;
    Ul[wi] = (unsigned short)lo;
}

// ---------------- pre = x @ W + bias  (MFMA, 3-term split-bf16) --------------
__global__ __launch_bounds__(256) void k_preM(const unsigned short* __restrict__ Wh,
                                              const unsigned short* __restrict__ Wl,
                                              const unsigned short* __restrict__ Xh,
                                              const unsigned short* __restrict__ Xl,
                                              const float* __restrict__ bias,
                                              float* __restrict__ preF,
                                              int s0, int flip) {
    int sl = blockIdx.x;
    int cg = blockIdx.y;
    int s = s0 + sl;
    int t_in = flip ? (TQ - 1 - s) : s;
    int tid = threadIdx.x;
    int w = tid >> 6, l = tid & 63;

    f32x4 acc[2][4];
    f32x4 zv = {0.f, 0.f, 0.f, 0.f};
#pragma unroll
    for (int cc = 0; cc < 2; ++cc)
#pragma unroll
        for (int bt = 0; bt < 4; ++bt) acc[cc][bt] = zv;

    size_t xb = (size_t)(1 + t_in) * (4 * 16 * 512);

#pragma unroll 2
    for (int kt = 0; kt < 16; ++kt) {
        bf16x8 ah[2], al[2], bh[4], bl[4];
#pragma unroll
        for (int cc = 0; cc < 2; ++cc) {
            size_t a = ((size_t)(cg * 8 + w * 2 + cc) * 16 + kt) * 512 + l * 8;
            ah[cc] = *(const bf16x8*)(Wh + a);
            al[cc] = *(const bf16x8*)(Wl + a);
        }
#pragma unroll
        for (int bt = 0; bt < 4; ++bt) {
            size_t a = xb + ((size_t)(bt * 16 + kt)) * 512 + l * 8;
            bh[bt] = *(const bf16x8*)(Xh + a);
            bl[bt] = *(const bf16x8*)(Xl + a);
        }
#pragma unroll
        for (int cc = 0; cc < 2; ++cc)
#pragma unroll
            for (int bt = 0; bt < 4; ++bt) {
                acc[cc][bt] = __builtin_amdgcn_mfma_f32_16x16x32_bf16(ah[cc], bh[bt], acc[cc][bt], 0, 0, 0);
                acc[cc][bt] = __builtin_amdgcn_mfma_f32_16x16x32_bf16(al[cc], bh[bt], acc[cc][bt], 0, 0, 0);
                acc[cc][bt] = __builtin_amdgcn_mfma_f32_16x16x32_bf16(ah[cc], bl[bt], acc[cc][bt], 0, 0, 0);
            }
    }

#pragma unroll
    for (int cc = 0; cc < 2; ++cc) {
        int ctg = cg * 8 + w * 2 + cc;
#pragma unroll
        for (int r = 0; r < 4; ++r) {
            int c = ctg * 16 + (l >> 4) * 4 + r;
            float bv = bias[c];
#pragma unroll
            for (int bt = 0; bt < 4; ++bt)
                preF[((size_t)sl * GQ + c) * 64 + bt * 16 + (l & 15)] = acc[cc][bt][r] + bv;
        }
    }
}

// ---------------- persistent LSTM layer ----------------
// 64 WGs x 512 thr. WG owns 8 units. wave w: kh=w>>1 (k-quarter), mh=w&1.
// U hi+lo register-resident. Producer flags replace the global barrier:
// wave kh depends on producer WGs [kh*16, kh*16+16). h stores via LDS repack
// into full 16B coalesced sc1 stores.
__global__ __launch_bounds__(512, 1) void k_layer(
    const unsigned short* __restrict__ Uh,
    const unsigned short* __restrict__ Ul,
    const float* __restrict__ preF,     // [sl][c][b]
    const int* __restrict__ mask,
    unsigned short* __restrict__ Xh,    // exchange + next-layer x frags
    unsigned short* __restrict__ Xl,
    float* __restrict__ xT32,           // [s][j][b] fp32 (k_out input), layer 3 only
    float* __restrict__ cT,
    float* __restrict__ hT,
    unsigned* __restrict__ bar,
    int s0, int nsteps, int flip, int writeX)
{
    __shared__ float part[128 * 65];    // 33.3 KB reduce buffer
    __shared__ unsigned hlds[8][64];    // hi | lo<<16 per (unit, b)

    int wg = blockIdx.x;
    int tid = threadIdx.x;
    int w = tid >> 6, l = tid & 63;
    int kh = w >> 1, mh = w & 1;
    int jglob = wg * 8 + w;

    // resident U fragments (hi + lo) for this wave's k-quarter
    bf16x8 BH[4][2], BL[4][2];
#pragma unroll
    for (int kt2 = 0; kt2 < 4; ++kt2)
#pragma unroll
        for (int nt = 0; nt < 2; ++nt) {
            size_t a = (((size_t)wg * 16 + (kh * 4 + kt2)) * 2 + nt) * 512 + l * 8;
            BH[kt2][nt] = *(const bf16x8*)(Uh + a);
            BL[kt2][nt] = *(const bf16x8*)(Ul + a);
        }

    float creg = cT[(size_t)jglob * 64 + l];
    float hpre = hT[(size_t)jglob * 64 + l];

    // prefetch finish operands for first step
    float pzv[4];
    int maskv;
    {
        int t0 = flip ? (TQ - 1 - s0) : s0;
        maskv = mask[l * TQ + t0];
#pragma unroll
        for (int g = 0; g < 4; ++g)
            pzv[g] = preF[((size_t)(g * 512 + wg * 8 + w)) * 64 + l];
    }

    for (int sl = 0; sl < nsteps; ++sl) {
        int s = s0 + sl;

        // wait for this wave's 16 producer WGs to have published frame s
        if (l < 16) {
            const unsigned* fp = bar + (size_t)(kh * 16 + l) * 16;
            while (__hip_atomic_load(fp, __ATOMIC_RELAXED, __HIP_MEMORY_SCOPE_AGENT)
                   < (unsigned)sl)
                __builtin_amdgcn_s_sleep(1);
        }

        // A (h) fragment loads (L1-bypass, L2-shared)
        bf16x8 AH[2][4], AL[2][4];
        size_t fb = (size_t)s * (4 * 16 * 512);
#pragma unroll
        for (int mt2 = 0; mt2 < 2; ++mt2)
#pragma unroll
            for (int kt2 = 0; kt2 < 4; ++kt2) {
                int mt = mh * 2 + mt2;
                int kt = kh * 4 + kt2;
                size_t a = fb + ((size_t)(mt * 16 + kt)) * 512 + (size_t)l * 8;
                AH[mt2][kt2] = frag_load16(Xh + a);
                AL[mt2][kt2] = frag_load16(Xl + a);
            }
        asm volatile("s_waitcnt vmcnt(0)" ::: "memory");
        __builtin_amdgcn_sched_barrier(0);

        f32x4 acc[2][2];
        f32x4 zv = {0.f, 0.f, 0.f, 0.f};
#pragma unroll
        for (int mt2 = 0; mt2 < 2; ++mt2)
#pragma unroll
            for (int nt = 0; nt < 2; ++nt) acc[mt2][nt] = zv;

#pragma unroll
        for (int kt2 = 0; kt2 < 4; ++kt2)
#pragma unroll
            for (int nt = 0; nt < 2; ++nt) {
                acc[0][nt] = __builtin_amdgcn_mfma_f32_16x16x32_bf16(AH[0][kt2], BH[kt2][nt], acc[0][nt], 0, 0, 0);
                acc[1][nt] = __builtin_amdgcn_mfma_f32_16x16x32_bf16(AH[1][kt2], BH[kt2][nt], acc[1][nt], 0, 0, 0);
                acc[0][nt] = __builtin_amdgcn_mfma_f32_16x16x32_bf16(AL[0][kt2], BH[kt2][nt], acc[0][nt], 0, 0, 0);
                acc[1][nt] = __builtin_amdgcn_mfma_f32_16x16x32_bf16(AL[1][kt2], BH[kt2][nt], acc[1][nt], 0, 0, 0);
                acc[0][nt] = __builtin_amdgcn_mfma_f32_16x16x32_bf16(AH[0][kt2], BL[kt2][nt], acc[0][nt], 0, 0, 0);
                acc[1][nt] = __builtin_amdgcn_mfma_f32_16x16x32_bf16(AH[1][kt2], BL[kt2][nt], acc[1][nt], 0, 0, 0);
            }

        // dump partials
#pragma unroll
        for (int mt2 = 0; mt2 < 2; ++mt2)
#pragma unroll
            for (int nt = 0; nt < 2; ++nt)
#pragma unroll
                for (int r = 0; r < 4; ++r)
                    part[((kh * 2 + nt) * 16 + (l & 15)) * 65 +
                         (mh * 32 + mt2 * 16 + (l >> 4) * 4 + r)] = acc[mt2][nt][r];
        __syncthreads();

        // balanced finish: this thread owns (unit = w, batch = l)
        float z[4];
#pragma unroll
        for (int g = 0; g < 4; ++g) {
            float zz = pzv[g];
#pragma unroll
            for (int k2 = 0; k2 < 4; ++k2)
                zz += part[((k2 * 2 + (g >> 1)) * 16 + ((g & 1) * 8 + w)) * 65 + l];
            z[g] = zz;
        }
        float ig = sigf(z[0]);
        float fg = sigf(z[1]);
        float gg = tanhfast(z[2]);
        float og = sigf(z[3]);
        float cn = fg * creg + ig * gg;
        float hn = og * tanhfast(cn);
        bool mk = maskv != 0;
        float ho = mk ? hn : hpre;
        creg = mk ? cn : creg;
        hpre = ho;

        unsigned hi = f2bf(ho);
        unsigned lo = f2bf(ho - bf2f(hi));
        hlds[w][l] = hi | (lo << 16);
        if (writeX)
            xT32[((size_t)s * DQ + jglob) * 64 + l] = ho;
        __syncthreads();

        // repack: 128 threads emit one 16B coalesced coherent store each
        if (tid < 128) {
            int plane = tid >> 6;
            int b = tid & 63;
            unsigned v[8];
#pragma unroll
            for (int u = 0; u < 8; ++u) v[u] = hlds[u][b];
            u32x4 d;
            if (plane == 0) {
#pragma unroll
                for (int i = 0; i < 4; ++i)
                    d[i] = (v[2 * i] & 0xffffu) | (v[2 * i + 1] << 16);
            } else {
#pragma unroll
                for (int i = 0; i < 4; ++i)
                    d[i] = (v[2 * i] >> 16) | (v[2 * i + 1] & 0xffff0000u);
            }
            size_t wi = (((size_t)(s + 1) * 4 + (b >> 4)) * 16 + (wg >> 2)) * 512 +
                        ((wg & 3) * 16 + (b & 15)) * 8;
            unsigned short* dst = (plane ? Xl : Xh) + wi;
            asm volatile("global_store_dwordx4 %0, %1, off sc0 sc1" :: "v"(dst), "v"(d));
            asm volatile("s_waitcnt vmcnt(0)" ::: "memory");
        }
        __syncthreads();

        if (tid == 0)
            __hip_atomic_store(&bar[(size_t)wg * 16], (unsigned)(sl + 1),
                               __ATOMIC_RELAXED, __HIP_MEMORY_SCOPE_AGENT);

        // prefetch next step's finish operands (latency hides under next poll+MFMA)
        if (sl + 1 < nsteps) {
            int t1 = flip ? (TQ - 1 - (s + 1)) : (s + 1);
            maskv = mask[l * TQ + t1];
#pragma unroll
            for (int g = 0; g < 4; ++g)
                pzv[g] = preF[((size_t)(sl + 1) * GQ + g * 512 + wg * 8 + w) * 64 + l];
        }
    }

    cT[(size_t)jglob * 64 + l] = creg;
    hT[(size_t)jglob * 64 + l] = hpre;
}

// ---------------- logits = x @ Wout + bout ----------------
__global__ __launch_bounds__(256) void k_out(const float* __restrict__ xT,
                                             const float* __restrict__ Wo,
                                             const float* __restrict__ bo,
                                             float* __restrict__ out) {
    __shared__ float WoL[64 * 64];
    int t = blockIdx.x;
    int tid = threadIdx.x;
    int b = tid & 63;
    int q = tid >> 6;
    float acc[16];
#pragma unroll
    for (int i = 0; i < 16; ++i) acc[i] = 0.f;

    for (int kc = 0; kc < 8; ++kc) {
        __syncthreads();
#pragma unroll
        for (int uu = 0; uu < 4; ++uu)
            *(float4*)&WoL[tid * 16 + uu * 4] =
                *(const float4*)&Wo[kc * 4096 + tid * 16 + uu * 4];
        __syncthreads();
        for (int kk = 0; kk < 64; ++kk) {
            float xv = xT[((size_t)t * DQ + kc * 64 + kk) * 64 + b];
#pragma unroll
            for (int uu = 0; uu < 4; ++uu) {
                float4 wv = *(const float4*)&WoL[kk * 64 + q * 16 + uu * 4];
                acc[uu * 4 + 0] += xv * wv.x;
                acc[uu * 4 + 1] += xv * wv.y;
                acc[uu * 4 + 2] += xv * wv.z;
                acc[uu * 4 + 3] += xv * wv.w;
            }
        }
    }
#pragma unroll
    for (int uu = 0; uu < 4; ++uu) {
        int n = q * 16 + uu * 4;
        float4 v = {acc[uu * 4 + 0] + bo[n + 0], acc[uu * 4 + 1] + bo[n + 1],
                    acc[uu * 4 + 2] + bo[n + 2], acc[uu * 4 + 3] + bo[n + 3]};
        *(float4*)&out[((size_t)(b * TQ + t)) * 64 + n] = v;
    }
}

extern "C" void kernel_launch(void* const* d_in, const int* in_sizes, int n_in,
                              void* d_out, int out_size, void* d_ws, size_t ws_size,
                              hipStream_t stream) {
    const int*   wid  = (const int*)d_in[0];
    const int*   pid  = (const int*)d_in[1];
    const int*   mask = (const int*)d_in[2];
    const float* emb  = (const float*)d_in[3];
    const float* Ws   = (const float*)d_in[4];
    const float* Us   = (const float*)d_in[5];
    const float* bs   = (const float*)d_in[6];
    const float* Wo   = (const float*)d_in[7];
    const float* bo   = (const float*)d_in[8];
    float* out = (float*)d_out;

    const size_t XFPLANE = (size_t)257 * 32768;      // shorts per plane
    char* p = (char*)d_ws;
    float* xRaw = (float*)p;                 p += 33554432;   // fp32 x / xT32
    unsigned short* XFA = (unsigned short*)p; p += 2 * XFPLANE * 2;
    unsigned short* XFB = (unsigned short*)p; p += 2 * XFPLANE * 2;
    unsigned short* UFh = (unsigned short*)p; p += 8388608;
    unsigned short* UFl = (unsigned short*)p; p += 8388608;
    unsigned short* WFh = (unsigned short*)p; p += 8388608;
    unsigned short* WFl = (unsigned short*)p; p += 8388608;
    float* cT = (float*)p;                   p += 131072;
    float* hT = (float*)p;                   p += 131072;
    unsigned* bar = (unsigned*)p;            p += 4096;
    float* preF = (float*)p;

    size_t base_bytes = (size_t)(p - (char*)d_ws);
    int CHUNK = 256;
    while (CHUNK > 2 && base_bytes + (size_t)CHUNK * GQ * 64 * 4 > ws_size) CHUNK >>= 1;

    k_convU<<<16384, 256, 0, stream>>>(Us, UFh, UFl);
    k_convW<<<16384, 256, 0, stream>>>(Ws, WFh, WFl);
    k_embed<<<dim3(TQ, 8), 256, 0, stream>>>(wid, pid, emb, xRaw);
    k_convX<<<32768, 256, 0, stream>>>(xRaw, XFA, XFA + XFPLANE);

    for (int layer = 0; layer < 4; ++layer) {
        int flip = layer & 1;
        int writeX = (layer == 3) ? 1 : 0;
        const float* bias = bs + (size_t)layer * GQ;
        const unsigned short* UFh_l = UFh + (size_t)layer * 1048576;
        const unsigned short* UFl_l = UFl + (size_t)layer * 1048576;
        const unsigned short* WFh_l = WFh + (size_t)layer * 1048576;
        const unsigned short* WFl_l = WFl + (size_t)layer * 1048576;
        unsigned short* Xi = (layer & 1) ? XFB : XFA;
        unsigned short* Xo = (layer & 1) ? XFA : XFB;

        hipMemsetAsync(cT, 0, 262144, stream);                 // cT + hT
        hipMemsetAsync(Xo, 0, 65536, stream);                  // frame 0 hi
        hipMemsetAsync(Xo + XFPLANE, 0, 65536, stream);        // frame 0 lo

        for (int s0 = 0; s0 < TQ; s0 += CHUNK) {
            dim3 g(CHUNK, 16);
            k_preM<<<g, 256, 0, stream>>>(WFh_l, WFl_l, Xi, Xi + XFPLANE,
                                          bias, preF, s0, flip);
            hipMemsetAsync(bar, 0, 4096, stream);
            k_layer<<<LWG, 512, 0, stream>>>(UFh_l, UFl_l, preF, mask,
                                             Xo, Xo + XFPLANE, xRaw, cT, hT, bar,
                                             s0, CHUNK, flip, writeX);
        }
    }

    k_out<<<TQ, 256, 0, stream>>>(xRaw, Wo, bo, out);
}

// Round 8
// 3264.757 us; speedup vs baseline: 7.0541x; 1.3049x over previous
//
#include <hip/hip_runtime.h>
#include <math.h>

#define TQ 256
#define DQ 512
#define GQ 2048

typedef __attribute__((ext_vector_type(8))) short bf16x8;
typedef __attribute__((ext_vector_type(4))) float f32x4;
typedef __attribute__((ext_vector_type(4))) unsigned u32x4;

__device__ __forceinline__ unsigned f2bf(float x) {
    unsigned u = __builtin_bit_cast(unsigned, x);
    return (u + 0x7fffu + ((u >> 16) & 1u)) >> 16;
}
__device__ __forceinline__ float bf2f(unsigned s) {
    return __builtin_bit_cast(float, s << 16);
}
__device__ __forceinline__ float sigf(float x) { return 1.f / (1.f + __expf(-x)); }
__device__ __forceinline__ float tanhfast(float x) { return 1.f - 2.f / (__expf(2.f * x) + 1.f); }

// L1-bypass 16B load (frames are write-once per layer; L2 fills are fresh)
__device__ __forceinline__ bf16x8 frag_load16(const unsigned short* p) {
    bf16x8 r;
    asm volatile("global_load_dwordx4 %0, %1, off sc0" : "=v"(r) : "v"(p));
    return r;
}

// ---------------- embedding + predicate concat -> xRaw[t][d][b] --------------
__global__ __launch_bounds__(256) void k_embed(const int* __restrict__ wid,
                                               const int* __restrict__ pid,
                                               const float* __restrict__ emb,
                                               float* __restrict__ xT) {
    __shared__ float Ls[64][65];
    int t = blockIdx.x;
    int d0 = blockIdx.y * 64;
    int tid = threadIdx.x;
    int l = tid & 63;
    int grp = tid >> 6;
#pragma unroll 4
    for (int bb = 0; bb < 16; ++bb) {
        int b = grp * 16 + bb;
        int d = d0 + l;
        float v;
        if (d < 511) v = emb[(size_t)wid[b * TQ + t] * 511 + d];
        else         v = (float)pid[b * TQ + t];
        Ls[l][b] = v;
    }
    __syncthreads();
#pragma unroll 4
    for (int dd = 0; dd < 16; ++dd) {
        int dl = grp * 16 + dd;
        xT[((size_t)t * DQ + d0 + dl) * 64 + l] = Ls[dl][l];
    }
}

// ---------------- xRaw -> x fragments (layer-0 input) ------------------------
__global__ __launch_bounds__(256) void k_convX(const float* __restrict__ xT,
                                               unsigned short* __restrict__ Xh,
                                               unsigned short* __restrict__ Xl) {
    int idx = blockIdx.x * 256 + threadIdx.x;    // (t*512 + d)*64 + b
    int b = idx & 63;
    int d = (idx >> 6) & 511;
    int t = idx >> 15;
    float v = xT[idx];
    unsigned hi = f2bf(v);
    unsigned lo = f2bf(v - bf2f(hi));
    size_t wi = (((size_t)(1 + t) * 4 + (b >> 4)) * 16 + (d >> 5)) * 512 +
                (((d >> 3) & 3) * 16 + (b & 15)) * 8 + (d & 7);
    Xh[wi] = (unsigned short)hi;
    Xl[wi] = (unsigned short)lo;
}

// ---------------- W -> A-operand fragments (m = col) -------------------------
__global__ __launch_bounds__(256) void k_convW(const float* __restrict__ Ws,
                                               unsigned short* __restrict__ Wh,
                                               unsigned short* __restrict__ Wl) {
    int idx = blockIdx.x * 256 + threadIdx.x;    // (lay*512 + d)*2048 + c
    int c = idx & 2047;
    int d = (idx >> 11) & 511;
    int lay = idx >> 20;
    float v = Ws[idx];
    unsigned hi = f2bf(v);
    unsigned lo = f2bf(v - bf2f(hi));
    size_t wi = (((size_t)lay * 128 + (c >> 4)) * 16 + (d >> 5)) * 512 +
                (((d >> 3) & 3) * 16 + (c & 15)) * 8 + (d & 7);
    Wh[wi] = (unsigned short)hi;
    Wl[wi] = (unsigned short)lo;
}

// ---------------- U -> B-operand fragments (n = (g&1)*8 + jl) ----------------
__global__ __launch_bounds__(256) void k_convU(const float* __restrict__ Us,
                                               unsigned short* __restrict__ Uh,
                                               unsigned short* __restrict__ Ul) {
    int idx = blockIdx.x * 256 + threadIdx.x;    // (lay*512 + k)*2048 + c
    int c = idx & 2047;
    int k = (idx >> 11) & 511;
    int lay = idx >> 20;
    float v = Us[idx];
    unsigned hi = f2bf(v);
    unsigned lo = f2bf(v - bf2f(hi));
    int g = c >> 9;
    int o = (c >> 3) & 63;
    int jl = c & 7;
    int nt = g >> 1;
    int n = (g & 1) * 8 + jl;
    size_t wi = ((((size_t)lay * 64 + o) * 16 + (k >> 5)) * 2 + nt) * 512 +
                (((k >> 3) & 3) * 16 + n) * 8 + (k & 7);
    Uh[wi] = (unsigned short)hi;
    Ul[wi] = (unsigned short)lo;
}

// ---------------- fused layer kernel ----------------
// grid = 256 WGs x 512 thr. WG < 128: recurrence (o = wg>>1 owns 8 units,
// half = wg&1 owns 32 batch). WG >= 128: pre-producer (x@W tiles + per-sl flag).
__global__ __launch_bounds__(512, 1) void k_fused(
    const unsigned short* __restrict__ Uh, const unsigned short* __restrict__ Ul,
    const unsigned short* __restrict__ Wh, const unsigned short* __restrict__ Wl,
    const unsigned short* __restrict__ Xih, const unsigned short* __restrict__ Xil,
    unsigned short* __restrict__ Xoh, unsigned short* __restrict__ Xol,
    float* __restrict__ preF, const int* __restrict__ mask,
    const float* __restrict__ bias, float* __restrict__ xT32,
    unsigned* __restrict__ bar, int flip, int writeX)
{
    __shared__ char ldsraw[81920];     // force 1 WG/CU; union of roles
    int wg = blockIdx.x;
    int tid = threadIdx.x;
    int w = tid >> 6, l = tid & 63;
    unsigned* pre_cnt = bar + 1024;

    if (wg >= 128) {
        // ================= pre-producer role =================
        float* stage = (float*)ldsraw + w * (16 * 68);
        int q = wg - 128;
        for (int T = q; T < 4096; T += 128) {
            int sl = T >> 4, cg = T & 15;
            int t_in = flip ? (255 - sl) : sl;
            int ct = cg * 8 + w;
            size_t xb = (size_t)(1 + t_in) * 32768 + (size_t)l * 8;
            f32x4 acc[4];
            f32x4 zv = {0.f, 0.f, 0.f, 0.f};
#pragma unroll
            for (int bt = 0; bt < 4; ++bt) acc[bt] = zv;

#pragma unroll 2
            for (int kt = 0; kt < 16; ++kt) {
                size_t wa = ((size_t)ct * 16 + kt) * 512 + l * 8;
                bf16x8 ah = *(const bf16x8*)(Wh + wa);
                bf16x8 al = *(const bf16x8*)(Wl + wa);
                bf16x8 bh[4], bo[4];
#pragma unroll
                for (int bt = 0; bt < 4; ++bt) {
                    size_t a = xb + (size_t)(bt * 16 + kt) * 512;
                    bh[bt] = *(const bf16x8*)(Xih + a);
                    bo[bt] = *(const bf16x8*)(Xil + a);
                }
#pragma unroll
                for (int bt = 0; bt < 4; ++bt) {
                    acc[bt] = __builtin_amdgcn_mfma_f32_16x16x32_bf16(ah, bh[bt], acc[bt], 0, 0, 0);
                    acc[bt] = __builtin_amdgcn_mfma_f32_16x16x32_bf16(al, bh[bt], acc[bt], 0, 0, 0);
                    acc[bt] = __builtin_amdgcn_mfma_f32_16x16x32_bf16(ah, bo[bt], acc[bt], 0, 0, 0);
                }
            }
            // stage (wave-local) then 16B coherent stores
#pragma unroll
            for (int bt = 0; bt < 4; ++bt)
#pragma unroll
                for (int r = 0; r < 4; ++r)
                    stage[((l >> 4) * 4 + r) * 68 + bt * 16 + (l & 15)] = acc[bt][r];
#pragma unroll
            for (int p = 0; p < 4; ++p) {
                int cr = p * 4 + (l >> 4);
                float bv = bias[ct * 16 + cr];
                f32x4 v = *(f32x4*)&stage[cr * 68 + (l & 15) * 4];
                v[0] += bv; v[1] += bv; v[2] += bv; v[3] += bv;
                float* dst = &preF[((size_t)sl * GQ + ct * 16 + cr) * 64 + (l & 15) * 4];
                asm volatile("global_store_dwordx4 %0, %1, off sc0 sc1" :: "v"(dst), "v"(v));
            }
            __syncthreads();   // drains vmcnt for all waves
            if (tid == 0)
                __hip_atomic_fetch_add(&pre_cnt[sl], 1u, __ATOMIC_RELAXED,
                                       __HIP_MEMORY_SCOPE_AGENT);
        }
        return;
    }

    // ================= recurrence role =================
    int o = wg >> 1, half = wg & 1;
    int kh = w >> 1, mq = w & 1;
    int mt = half * 2 + mq;            // global 16-batch tile
    float* part = (float*)ldsraw;      // [128][33]
    unsigned* hlds = (unsigned*)(ldsraw + 16896);  // [8][32]

    // resident U fragments (hi + lo) for this wave's k-quarter
    bf16x8 BH[4][2], BL[4][2];
#pragma unroll
    for (int kt2 = 0; kt2 < 4; ++kt2)
#pragma unroll
        for (int nt = 0; nt < 2; ++nt) {
            size_t a = (((size_t)o * 16 + kh * 4 + kt2) * 2 + nt) * 512 + l * 8;
            BH[kt2][nt] = *(const bf16x8*)(Uh + a);
            BL[kt2][nt] = *(const bf16x8*)(Ul + a);
        }

    int u8 = (tid >> 5) & 7;
    int bl = tid & 31;
    int jglob = o * 8 + u8;
    int bglob = half * 32 + bl;
    bool fin = tid < 256;

    float creg = 0.f, hpre = 0.f;
    float pzv[4];
    int maskv = 0;

    // prologue: wait for pre of sl=0, then prefetch finish operands
    if (tid == 0) {
        while (__hip_atomic_load(&pre_cnt[0], __ATOMIC_RELAXED,
                                 __HIP_MEMORY_SCOPE_AGENT) < 16u)
            __builtin_amdgcn_s_sleep(1);
    }
    __syncthreads();
    if (fin) {
        int t0 = flip ? 255 : 0;
        maskv = mask[bglob * TQ + t0];
#pragma unroll
        for (int g = 0; g < 4; ++g)
            pzv[g] = preF[(size_t)(g * 512 + jglob) * 64 + bglob];
    }

    for (int sl = 0; sl < 256; ++sl) {
        // poll producer flags for frame sl (16 producers per wave)
        if (l < 16) {
            const unsigned* fp = bar + ((((kh * 16 + l) << 1) | half) << 3);
            while (__hip_atomic_load(fp, __ATOMIC_RELAXED,
                                     __HIP_MEMORY_SCOPE_AGENT) < (unsigned)sl)
                __builtin_amdgcn_s_sleep(1);
        }
        if (tid == 256 && sl < 255) {
            while (__hip_atomic_load(&pre_cnt[sl + 1], __ATOMIC_RELAXED,
                                     __HIP_MEMORY_SCOPE_AGENT) < 16u)
                __builtin_amdgcn_s_sleep(1);
        }

        // A (h) fragment loads for (mt, kh)
        bf16x8 AH[4], AL[4];
        size_t fb = (size_t)sl * 32768 + (size_t)(mt * 16 + kh * 4) * 512 + (size_t)l * 8;
#pragma unroll
        for (int kt2 = 0; kt2 < 4; ++kt2) {
            AH[kt2] = frag_load16(Xoh + fb + kt2 * 512);
            AL[kt2] = frag_load16(Xol + fb + kt2 * 512);
        }
        asm volatile("s_waitcnt vmcnt(0)" ::: "memory");
        __builtin_amdgcn_sched_barrier(0);

        f32x4 acc0 = {0.f, 0.f, 0.f, 0.f};
        f32x4 acc1 = {0.f, 0.f, 0.f, 0.f};
#pragma unroll
        for (int kt2 = 0; kt2 < 4; ++kt2) {
            acc0 = __builtin_amdgcn_mfma_f32_16x16x32_bf16(AH[kt2], BH[kt2][0], acc0, 0, 0, 0);
            acc1 = __builtin_amdgcn_mfma_f32_16x16x32_bf16(AH[kt2], BH[kt2][1], acc1, 0, 0, 0);
            acc0 = __builtin_amdgcn_mfma_f32_16x16x32_bf16(AL[kt2], BH[kt2][0], acc0, 0, 0, 0);
            acc1 = __builtin_amdgcn_mfma_f32_16x16x32_bf16(AL[kt2], BH[kt2][1], acc1, 0, 0, 0);
            acc0 = __builtin_amdgcn_mfma_f32_16x16x32_bf16(AH[kt2], BL[kt2][0], acc0, 0, 0, 0);
            acc1 = __builtin_amdgcn_mfma_f32_16x16x32_bf16(AH[kt2], BL[kt2][1], acc1, 0, 0, 0);
        }

        // dump partials: part[(kh*2+nt)*16 + n][b_local]
#pragma unroll
        for (int r = 0; r < 4; ++r) {
            int col = mq * 16 + (l >> 4) * 4 + r;
            part[((kh * 2 + 0) * 16 + (l & 15)) * 33 + col] = acc0[r];
            part[((kh * 2 + 1) * 16 + (l & 15)) * 33 + col] = acc1[r];
        }
        __syncthreads();    // (1)

        if (fin) {
            float z[4];
#pragma unroll
            for (int g = 0; g < 4; ++g) {
                float zz = pzv[g];
#pragma unroll
                for (int k2 = 0; k2 < 4; ++k2)
                    zz += part[((k2 * 2 + (g >> 1)) * 16 + (g & 1) * 8 + u8) * 33 + bl];
                z[g] = zz;
            }
            float ig = sigf(z[0]);
            float fg = sigf(z[1]);
            float gg = tanhfast(z[2]);
            float og = sigf(z[3]);
            float cn = fg * creg + ig * gg;
            float hn = og * tanhfast(cn);
            bool mk = maskv != 0;
            float ho = mk ? hn : hpre;
            creg = mk ? cn : creg;
            hpre = ho;
            if (writeX)
                xT32[((size_t)sl * DQ + jglob) * 64 + bglob] = ho;
            unsigned hi = f2bf(ho);
            unsigned lo = f2bf(ho - bf2f(hi));
            hlds[u8 * 32 + bl] = hi | (lo << 16);
        }
        __syncthreads();    // (2)

        // wave 7 (non-finisher): repack + coherent 16B stores + drain + flag
        if (w == 7) {
            int plane = l >> 5, b2 = l & 31;
            int bg = half * 32 + b2;
            unsigned v[8];
#pragma unroll
            for (int u = 0; u < 8; ++u) v[u] = hlds[u * 32 + b2];
            u32x4 d;
            if (plane == 0) {
#pragma unroll
                for (int i = 0; i < 4; ++i)
                    d[i] = (v[2 * i] & 0xffffu) | (v[2 * i + 1] << 16);
            } else {
#pragma unroll
                for (int i = 0; i < 4; ++i)
                    d[i] = (v[2 * i] >> 16) | (v[2 * i + 1] & 0xffff0000u);
            }
            size_t wi = (((size_t)(sl + 1) * 4 + (bg >> 4)) * 16 + (o >> 2)) * 512 +
                        ((o & 3) * 16 + (bg & 15)) * 8;
            unsigned short* dst = (plane ? Xol : Xoh) + wi;
            asm volatile("global_store_dwordx4 %0, %1, off sc0 sc1" :: "v"(dst), "v"(d));
            asm volatile("s_waitcnt vmcnt(0)" ::: "memory");
            if (l == 0)
                __hip_atomic_store(&bar[wg * 8], (unsigned)(sl + 1),
                                   __ATOMIC_RELAXED, __HIP_MEMORY_SCOPE_AGENT);
        }

        // prefetch next step's finish operands (ordered after this step's spins)
        if (fin && sl < 255) {
            int t1 = flip ? (254 - sl) : (sl + 1);
            maskv = mask[bglob * TQ + t1];
#pragma unroll
            for (int g = 0; g < 4; ++g)
                pzv[g] = preF[((size_t)(sl + 1) * GQ + g * 512 + jglob) * 64 + bglob];
        }
    }
}

// ---------------- logits = x @ Wout + bout ----------------
__global__ __launch_bounds__(256) void k_out(const float* __restrict__ xT,
                                             const float* __restrict__ Wo,
                                             const float* __restrict__ bo,
                                             float* __restrict__ out) {
    __shared__ float WoL[64 * 64];
    int t = blockIdx.x;
    int tid = threadIdx.x;
    int b = tid & 63;
    int q = tid >> 6;
    float acc[16];
#pragma unroll
    for (int i = 0; i < 16; ++i) acc[i] = 0.f;

    for (int kc = 0; kc < 8; ++kc) {
        __syncthreads();
#pragma unroll
        for (int uu = 0; uu < 4; ++uu)
            *(float4*)&WoL[tid * 16 + uu * 4] =
                *(const float4*)&Wo[kc * 4096 + tid * 16 + uu * 4];
        __syncthreads();
        for (int kk = 0; kk < 64; ++kk) {
            float xv = xT[((size_t)t * DQ + kc * 64 + kk) * 64 + b];
#pragma unroll
            for (int uu = 0; uu < 4; ++uu) {
                float4 wv = *(const float4*)&WoL[kk * 64 + q * 16 + uu * 4];
                acc[uu * 4 + 0] += xv * wv.x;
                acc[uu * 4 + 1] += xv * wv.y;
                acc[uu * 4 + 2] += xv * wv.z;
                acc[uu * 4 + 3] += xv * wv.w;
            }
        }
    }
#pragma unroll
    for (int uu = 0; uu < 4; ++uu) {
        int n = q * 16 + uu * 4;
        float4 v = {acc[uu * 4 + 0] + bo[n + 0], acc[uu * 4 + 1] + bo[n + 1],
                    acc[uu * 4 + 2] + bo[n + 2], acc[uu * 4 + 3] + bo[n + 3]};
        *(float4*)&out[((size_t)(b * TQ + t)) * 64 + n] = v;
    }
}

extern "C" void kernel_launch(void* const* d_in, const int* in_sizes, int n_in,
                              void* d_out, int out_size, void* d_ws, size_t ws_size,
                              hipStream_t stream) {
    const int*   wid  = (const int*)d_in[0];
    const int*   pid  = (const int*)d_in[1];
    const int*   mask = (const int*)d_in[2];
    const float* emb  = (const float*)d_in[3];
    const float* Ws   = (const float*)d_in[4];
    const float* Us   = (const float*)d_in[5];
    const float* bs   = (const float*)d_in[6];
    const float* Wo   = (const float*)d_in[7];
    const float* bo   = (const float*)d_in[8];
    float* out = (float*)d_out;

    const size_t XFPLANE = (size_t)257 * 32768;      // shorts per plane
    char* p = (char*)d_ws;
    float* xRaw = (float*)p;                  p += 33554432;
    unsigned short* XFA = (unsigned short*)p; p += 2 * XFPLANE * 2;
    unsigned short* XFB = (unsigned short*)p; p += 2 * XFPLANE * 2;
    unsigned short* UFh = (unsigned short*)p; p += 8388608;
    unsigned short* UFl = (unsigned short*)p; p += 8388608;
    unsigned short* WFh = (unsigned short*)p; p += 8388608;
    unsigned short* WFl = (unsigned short*)p; p += 8388608;
    unsigned* bar = (unsigned*)p;             p += 8192;
    float* preF = (float*)p;                  // 256*2048*64*4 = 134217728

    k_convU<<<16384, 256, 0, stream>>>(Us, UFh, UFl);
    k_convW<<<16384, 256, 0, stream>>>(Ws, WFh, WFl);
    k_embed<<<dim3(TQ, 8), 256, 0, stream>>>(wid, pid, emb, xRaw);
    k_convX<<<32768, 256, 0, stream>>>(xRaw, XFA, XFA + XFPLANE);

    for (int layer = 0; layer < 4; ++layer) {
        int flip = layer & 1;
        int writeX = (layer == 3) ? 1 : 0;
        const float* bias = bs + (size_t)layer * GQ;
        const unsigned short* UFh_l = UFh + (size_t)layer * 1048576;
        const unsigned short* UFl_l = UFl + (size_t)layer * 1048576;
        const unsigned short* WFh_l = WFh + (size_t)layer * 1048576;
        const unsigned short* WFl_l = WFl + (size_t)layer * 1048576;
        unsigned short* Xi = (layer & 1) ? XFB : XFA;
        unsigned short* Xo = (layer & 1) ? XFA : XFB;

        hipMemsetAsync(Xo, 0, 65536, stream);                  // frame 0 hi
        hipMemsetAsync(Xo + XFPLANE, 0, 65536, stream);        // frame 0 lo
        hipMemsetAsync(bar, 0, 8192, stream);                  // flags + pre_cnt

        k_fused<<<256, 512, 0, stream>>>(UFh_l, UFl_l, WFh_l, WFl_l,
                                         Xi, Xi + XFPLANE, Xo, Xo + XFPLANE,
                                         preF, mask, bias, xRaw, bar,
                                         flip, writeX);
    }

    k_out<<<TQ, 256, 0, stream>>>(xRaw, Wo, bo, out);
}